// Round 1
// 509.493 us; speedup vs baseline: 1.0583x; 1.0583x over previous
//
#include <hip/hip_runtime.h>

typedef unsigned short u16;
typedef unsigned int u32;
typedef __attribute__((ext_vector_type(8))) short bf16x8;
typedef __attribute__((ext_vector_type(4))) float f32x4;
struct __align__(8) us4 { u16 x, y, z, w; };

#define S_LEN 2048
#define HID   4096
#define NH    32
#define KVH   8
#define HD    128
#define MFMA16 __builtin_amdgcn_mfma_f32_16x16x32_bf16

__device__ inline u16 f2bf(float f) {
  u32 u = __float_as_uint(f);
  u32 r = (u + 0x7fffu + ((u >> 16) & 1u)) >> 16;  // RNE
  return (u16)r;
}
__device__ inline float bf2f(u16 h) { return __uint_as_float(((u32)h) << 16); }

__device__ inline void gld_lds16(const void* g, void* l) {
  __builtin_amdgcn_global_load_lds(
      (const __attribute__((address_space(1))) u32*)g,
      (__attribute__((address_space(3))) u32*)l, 16, 0, 0);
}

// ---------------- fused fp32 -> bf16 conversion (all 5 tensors, 1 launch) ---
__global__ __launch_bounds__(256)
void cvt_all(const float* __restrict__ x, const float* __restrict__ wq,
             const float* __restrict__ wk, const float* __restrict__ wv,
             const float* __restrict__ wo, u16* __restrict__ xb,
             u16* __restrict__ wqb, u16* __restrict__ wkb,
             u16* __restrict__ wvb, u16* __restrict__ wob) {
  int b = blockIdx.x;
  const float* in; u16* out; int base;
  if (b < 8192)       { in = x;  out = xb;  base = b; }
  else if (b < 24576) { in = wq; out = wqb; base = b - 8192; }
  else if (b < 28672) { in = wk; out = wkb; base = b - 24576; }
  else if (b < 32768) { in = wv; out = wvb; base = b - 28672; }
  else                { in = wo; out = wob; base = b - 32768; }
  size_t i = ((size_t)base * 256 + threadIdx.x) * 4;
  f32x4 v = *(const f32x4*)(in + i);
  us4 o;
  o.x = f2bf(v[0]); o.y = f2bf(v[1]); o.z = f2bf(v[2]); o.w = f2bf(v[3]);
  *(us4*)(out + i) = o;
}

// ---------------- 256x256 / BK=64 8-phase deep-pipelined NT GEMM core -------
// 512 threads = 8 waves (2 M-half x 4 N-quarter). Per-wave C: 128x64.
// LDS (dynamic 128 KiB): A bufs [0,64K) = 2 x 256x64 bf16; B bufs [64K,128K).
// Half-tile slot = 128 rows x 64 cols = 16 KiB. Swizzle: 16B col-slot s of row
// r physically stored at s^(r&7) (write side pre-swizzles the GLOBAL source,
// LDS dest stays linear for global_load_lds; read applies the same XOR).
//
// Per K-tile (4 phases, 2 barriers each):
//  P0: read A0(m0-3,k0-1)+B0(n0-1)  | stage (t+1).B1 -> other buf
//  P1: read B1(n2-3)                | stage (t+1).A1 -> other buf
//  P2: read A1(m4-7)                | stage (t+2).B0 -> THIS buf (B dead @P1)
//  P3: (regs only)                  | stage (t+2).A0 -> THIS buf (A dead @P2)
//  boundary: s_waitcnt vmcnt(4)  -> all of tile t+1 landed, 2 half-tiles of
//  t+2 still in flight (counted-vmcnt, never 0 mid-loop). Tail drains to 0.
__device__ __forceinline__ void stage_half(const u16* __restrict__ src, int ldk,
                                           int rowBase, int k0, char* lslot,
                                           int t) {
  int rl = t >> 3;
  int c8 = ((t & 7) ^ (rl & 7)) * 8;  // (r+64)&7 == r&7
  gld_lds16(src + (size_t)(rowBase + rl) * ldk + k0 + c8, lslot + t * 16);
  gld_lds16(src + (size_t)(rowBase + 64 + rl) * ldk + k0 + c8,
            lslot + 8192 + t * 16);
}

__device__ __forceinline__ void gemm256_core(
    const u16* __restrict__ A, const u16* __restrict__ W, int m0, int n0,
    int ldk, int kBeg, int kEnd, char* lds, f32x4 (&acc)[8][4]) {
  const int t = threadIdx.x;
  const int l = t & 63, w = t >> 6;
  const int l15 = l & 15, quad = l >> 4;
  const int wr = w >> 2, wcn = w & 3;
  const int nt = (kEnd - kBeg) >> 6;
  char* ldsA = lds;
  char* ldsB = lds + 65536;
  // fragment row ≡ l15 (mod 8) for every mIdx/n -> XOR term is frag-invariant
  const int swz0 = ((0 + quad) ^ (l15 & 7)) * 16;  // k-half 0
  const int swz1 = ((4 + quad) ^ (l15 & 7)) * 16;  // k-half 1
  const int aB0 = wr * 16384 + l15 * 128;
  const int bB0 = wcn * 8192 + l15 * 128;

#pragma unroll
  for (int m = 0; m < 8; m++)
#pragma unroll
    for (int n = 0; n < 4; n++) acc[m][n] = (f32x4){0.f, 0.f, 0.f, 0.f};

  // prologue: (0).B0 (0).A0 (0).B1 (0).A1 (1).B0 (1).A0   [steady-state order]
  stage_half(W, ldk, n0,       kBeg, ldsB,         t);
  stage_half(A, ldk, m0,       kBeg, ldsA,         t);
  stage_half(W, ldk, n0 + 128, kBeg, ldsB + 16384, t);
  stage_half(A, ldk, m0 + 128, kBeg, ldsA + 16384, t);
  if (nt > 1) {
    stage_half(W, ldk, n0, kBeg + 64, ldsB + 32768, t);
    stage_half(A, ldk, m0, kBeg + 64, ldsA + 32768, t);
    asm volatile("s_waitcnt vmcnt(4)" ::: "memory");
  } else {
    asm volatile("s_waitcnt vmcnt(0)" ::: "memory");
  }
  __builtin_amdgcn_s_barrier();

  bf16x8 a[4][2], b[2][2], b2[2][2];
#pragma unroll 1
  for (int tt = 0; tt < nt; ++tt) {
    const int d = tt & 1, dn = d ^ 1;
    const int aO = d * 32768 + aB0;
    const int bO = d * 32768 + bB0;
    const int k1 = kBeg + (tt + 1) * 64;
    const int k2 = k1 + 64;

    // ---- phase 0 : Q00 = A0 x B0 ----
#pragma unroll
    for (int m = 0; m < 4; m++) {
      a[m][0] = *(const bf16x8*)(ldsA + aO + m * 2048 + swz0);
      a[m][1] = *(const bf16x8*)(ldsA + aO + m * 2048 + swz1);
    }
#pragma unroll
    for (int n = 0; n < 2; n++) {
      b[n][0] = *(const bf16x8*)(ldsB + bO + n * 2048 + swz0);
      b[n][1] = *(const bf16x8*)(ldsB + bO + n * 2048 + swz1);
    }
    if (tt + 1 < nt) stage_half(W, ldk, n0 + 128, k1, ldsB + dn * 32768 + 16384, t);
    __builtin_amdgcn_s_barrier();
    __builtin_amdgcn_s_setprio(1);
#pragma unroll
    for (int m = 0; m < 4; m++)
#pragma unroll
      for (int n = 0; n < 2; n++) {
        acc[m][n] = MFMA16(a[m][0], b[n][0], acc[m][n], 0, 0, 0);
        acc[m][n] = MFMA16(a[m][1], b[n][1], acc[m][n], 0, 0, 0);
      }
    __builtin_amdgcn_s_setprio(0);
    __builtin_amdgcn_s_barrier();

    // ---- phase 1 : Q01 = A0 x B1 ----
#pragma unroll
    for (int n = 0; n < 2; n++) {
      b2[n][0] = *(const bf16x8*)(ldsB + bO + (2 + n) * 2048 + swz0);
      b2[n][1] = *(const bf16x8*)(ldsB + bO + (2 + n) * 2048 + swz1);
    }
    if (tt + 1 < nt) stage_half(A, ldk, m0 + 128, k1, ldsA + dn * 32768 + 16384, t);
    __builtin_amdgcn_s_barrier();
    __builtin_amdgcn_s_setprio(1);
#pragma unroll
    for (int m = 0; m < 4; m++)
#pragma unroll
      for (int n = 0; n < 2; n++) {
        acc[m][2 + n] = MFMA16(a[m][0], b2[n][0], acc[m][2 + n], 0, 0, 0);
        acc[m][2 + n] = MFMA16(a[m][1], b2[n][1], acc[m][2 + n], 0, 0, 0);
      }
    __builtin_amdgcn_s_setprio(0);
    __builtin_amdgcn_s_barrier();

    // ---- phase 2 : Q10 = A1 x B0 ----
#pragma unroll
    for (int m = 0; m < 4; m++) {
      a[m][0] = *(const bf16x8*)(ldsA + aO + (4 + m) * 2048 + swz0);
      a[m][1] = *(const bf16x8*)(ldsA + aO + (4 + m) * 2048 + swz1);
    }
    if (tt + 2 < nt) stage_half(W, ldk, n0, k2, ldsB + d * 32768, t);
    __builtin_amdgcn_s_barrier();
    __builtin_amdgcn_s_setprio(1);
#pragma unroll
    for (int m = 0; m < 4; m++)
#pragma unroll
      for (int n = 0; n < 2; n++) {
        acc[4 + m][n] = MFMA16(a[m][0], b[n][0], acc[4 + m][n], 0, 0, 0);
        acc[4 + m][n] = MFMA16(a[m][1], b[n][1], acc[4 + m][n], 0, 0, 0);
      }
    __builtin_amdgcn_s_setprio(0);
    __builtin_amdgcn_s_barrier();

    // ---- phase 3 : Q11 = A1 x B1 ----
    if (tt + 2 < nt) stage_half(A, ldk, m0, k2, ldsA + d * 32768, t);
    __builtin_amdgcn_s_barrier();
    __builtin_amdgcn_s_setprio(1);
#pragma unroll
    for (int m = 0; m < 4; m++)
#pragma unroll
      for (int n = 0; n < 2; n++) {
        acc[4 + m][2 + n] = MFMA16(a[m][0], b2[n][0], acc[4 + m][2 + n], 0, 0, 0);
        acc[4 + m][2 + n] = MFMA16(a[m][1], b2[n][1], acc[4 + m][2 + n], 0, 0, 0);
      }
    __builtin_amdgcn_s_setprio(0);
    if (tt + 1 < nt) {
      if (tt + 2 < nt) asm volatile("s_waitcnt vmcnt(4)" ::: "memory");
      else             asm volatile("s_waitcnt vmcnt(0)" ::: "memory");
    }
    __builtin_amdgcn_s_barrier();
  }
}

// ---------------- fused QKV projection (full K, no split) -------------------
__global__ __launch_bounds__(512, 2)
void gemm_qkv8(const u16* __restrict__ xb, const u16* __restrict__ wqb,
               const u16* __restrict__ wkb, const u16* __restrict__ wvb,
               u16* __restrict__ Qp, u16* __restrict__ Kp, u16* __restrict__ vt) {
  extern __shared__ char lds[];
  const int id = blockIdx.x;                 // 192 blocks, 192 % 8 == 0
  const int sw = (id & 7) * 24 + (id >> 3);  // XCD-bijective swizzle
  const int bx = sw % 24, by = sw / 24;
  const u16* W; u16* C; int n0, ldc, epi;
  if (bx < 16)      { W = wqb; C = Qp; n0 = bx * 256;        ldc = HID;  epi = 0; }
  else if (bx < 20) { W = wkb; C = Kp; n0 = (bx - 16) * 256; ldc = 1024; epi = 0; }
  else              { W = wvb; C = vt; n0 = (bx - 20) * 256; ldc = 0;    epi = 1; }
  const int m0 = by * 256;

  f32x4 acc[8][4];
  gemm256_core(xb, W, m0, n0, HID, 0, HID, lds, acc);

  const int t = threadIdx.x, l = t & 63, w = t >> 6;
  const int l15 = l & 15, quad = l >> 4;
  const int wr = w >> 2, wcn = w & 3;
  if (epi == 0) {
#pragma unroll
    for (int m = 0; m < 8; m++) {
      int row0 = m0 + wr * 128 + m * 16 + quad * 4;
#pragma unroll
      for (int n = 0; n < 4; n++) {
        int col = n0 + wcn * 64 + n * 16 + l15;
#pragma unroll
        for (int r = 0; r < 4; r++)
          C[(size_t)(row0 + r) * ldc + col] = f2bf(acc[m][n][r]);
      }
    }
  } else {
#pragma unroll
    for (int m = 0; m < 8; m++) {
      int row0 = m0 + wr * 128 + m * 16 + quad * 4;
#pragma unroll
      for (int n = 0; n < 4; n++) {
        int col = n0 + wcn * 64 + n * 16 + l15;  // V row index (0..1023)
        us4 v;
        v.x = f2bf(acc[m][n][0]); v.y = f2bf(acc[m][n][1]);
        v.z = f2bf(acc[m][n][2]); v.w = f2bf(acc[m][n][3]);
        *(us4*)(vt + (size_t)col * S_LEN + row0) = v;  // transposed store
      }
    }
  }
}

// ---------------- output projection, split-K x2 (256 blocks = full pack) ----
__global__ __launch_bounds__(512, 2)
void gemm_out8(const u16* __restrict__ ab, const u16* __restrict__ wob,
               float* __restrict__ O0, float* __restrict__ O1) {
  extern __shared__ char lds[];
  const int id = blockIdx.x;                 // 256 blocks
  const int sw = (id & 7) * 32 + (id >> 3);
  const int z = sw >> 7, rem = sw & 127;
  const int by = rem >> 4, bx = rem & 15;
  float* Op = z ? O1 : O0;

  f32x4 acc[8][4];
  gemm256_core(ab, wob, by * 256, bx * 256, HID, z * 2048, z * 2048 + 2048, lds, acc);

  const int t = threadIdx.x, l = t & 63, w = t >> 6;
  const int l15 = l & 15, quad = l >> 4;
  const int wr = w >> 2, wcn = w & 3;
#pragma unroll
  for (int m = 0; m < 8; m++) {
    int row0 = by * 256 + wr * 128 + m * 16 + quad * 4;
#pragma unroll
    for (int n = 0; n < 4; n++) {
      int col = bx * 256 + wcn * 64 + n * 16 + l15;
#pragma unroll
      for (int r = 0; r < 4; r++)
        Op[(size_t)(row0 + r) * HID + col] = acc[m][n][r];
    }
  }
}

__global__ __launch_bounds__(256)
void reduce_out(const float* __restrict__ O0, const float* __restrict__ O1,
                float* __restrict__ outp) {
  size_t i = ((size_t)blockIdx.x * 256 + threadIdx.x) * 4;
  f32x4 a = *(const f32x4*)(O0 + i);
  f32x4 b = *(const f32x4*)(O1 + i);
  a[0] += b[0]; a[1] += b[1]; a[2] += b[2]; a[3] += b[3];
  *(f32x4*)(outp + i) = a;
}

// ---------------- RMSNorm + RoPE relayout (single-source, no partials) ------
__global__ __launch_bounds__(256)
void rope_all(const u16* __restrict__ Qp, const u16* __restrict__ Kp,
              const float* __restrict__ qnw, const float* __restrict__ knw,
              const float* __restrict__ cosT, const float* __restrict__ sinT,
              const int* __restrict__ pos, u16* __restrict__ qbh,
              u16* __restrict__ kbh) {
  const int b = blockIdx.x;
  const int t = threadIdx.x, w = t >> 6, l = t & 63;
  const u16* xr; const float* nw; u16* orow; int s;
  if (b < 16384) {       // Q: NH=32 heads
    int p = b * 4 + w;
    s = p >> 5; int h = p & 31;
    xr = Qp + (size_t)s * HID + h * HD;
    nw = qnw;
    orow = qbh + ((size_t)h * S_LEN + s) * HD;
  } else {               // K: KVH=8 heads
    int p = (b - 16384) * 4 + w;
    s = p >> 3; int h = p & 7;
    xr = Kp + (size_t)s * 1024 + h * HD;
    nw = knw;
    orow = kbh + ((size_t)h * S_LEN + s) * HD;
  }
  float x1 = bf2f(xr[l]);
  float x2 = bf2f(xr[l + 64]);
  float ss = x1 * x1 + x2 * x2;
#pragma unroll
  for (int m = 1; m < 64; m <<= 1) ss += __shfl_xor(ss, m);
  float rinv = rsqrtf(ss * (1.0f / 128.0f) + 1e-6f);
  float n1 = x1 * rinv * nw[l];
  float n2 = x2 * rinv * nw[l + 64];
  int ps = pos[s];
  float c1 = cosT[ps * HD + l], s1 = sinT[ps * HD + l];
  float c2 = cosT[ps * HD + l + 64], s2 = sinT[ps * HD + l + 64];
  float y1 = n1 * c1 - n2 * s1;
  float y2 = n2 * c2 + n1 * s2;
  orow[l] = f2bf(y1);
  orow[l + 64] = f2bf(y2);
}

// ---------------- causal GQA flash attention (unchanged) --------------------
__global__ __launch_bounds__(256)
void attn_fwd(const u16* __restrict__ qh, const u16* __restrict__ kbh,
              const u16* __restrict__ vth, u16* __restrict__ ab) {
  __shared__ __align__(16) u16 lK[64 * 128];
  __shared__ __align__(16) u16 lV[128 * 64];
  __shared__ __align__(16) u16 lP[4][16 * 72];
  const int t = threadIdx.x, w = t >> 6, l = t & 63;
  const int quad = l >> 4, l15 = l & 15;
  const int h = blockIdx.x;
  const int qt = 31 - blockIdx.y;   // heavy blocks first
  const int kvh = h >> 2;
  const int q0 = qt * 64;
  const int qrow = q0 + w * 16 + l15;

  bf16x8 qf[4];
#pragma unroll
  for (int ks = 0; ks < 4; ks++)
    qf[ks] = *(const bf16x8*)(qh + ((size_t)h * S_LEN + qrow) * HD + ks * 32 + quad * 8);

  f32x4 accO[8];
#pragma unroll
  for (int j = 0; j < 8; j++) accO[j] = (f32x4){0.f, 0.f, 0.f, 0.f};
  float m_cur = -3.0e38f, l_sum = 0.f;
  const float scale = 0.08838834764831845f;

  const int ntiles = qt + 1;
  for (int tt = 0; tt < ntiles; tt++) {
    const int c0 = tt * 64;
#pragma unroll
    for (int i = 0; i < 4; i++) {
      int Cc = i * 256 + t;
      int r = Cc >> 4, ch = Cc & 15;
      int gch = ch ^ (r & 15);
      gld_lds16(kbh + ((size_t)kvh * S_LEN + c0 + r) * HD + gch * 8, lK + Cc * 8);
    }
#pragma unroll
    for (int i = 0; i < 4; i++) {
      int Cc = i * 256 + t;
      int d = Cc >> 3, ch = Cc & 7;
      int gch = ch ^ (d & 7);
      gld_lds16(vth + ((size_t)kvh * HD + d) * S_LEN + c0 + gch * 8, lV + Cc * 8);
    }
    __syncthreads();

    f32x4 st[4];
#pragma unroll
    for (int i = 0; i < 4; i++) {
      f32x4 sa = (f32x4){0.f, 0.f, 0.f, 0.f};
      int r = i * 16 + l15;
#pragma unroll
      for (int ks = 0; ks < 4; ks++) {
        int lc = ks * 4 + quad;
        bf16x8 kf = *(const bf16x8*)(lK + r * 128 + ((lc ^ (r & 15)) * 8));
        sa = __builtin_amdgcn_mfma_f32_16x16x32_bf16(kf, qf[ks], sa, 0, 0, 0);
      }
      st[i] = sa;
    }

    float tmax = -3.0e38f;
#pragma unroll
    for (int i = 0; i < 4; i++) {
#pragma unroll
      for (int r = 0; r < 4; r++) {
        int kcol = c0 + i * 16 + quad * 4 + r;
        float v = st[i][r] * scale;
        v = (kcol <= qrow) ? v : -3.0e38f;
        st[i][r] = v;
        tmax = fmaxf(tmax, v);
      }
    }
    tmax = fmaxf(tmax, __shfl_xor(tmax, 16));
    tmax = fmaxf(tmax, __shfl_xor(tmax, 32));
    float m_new = fmaxf(m_cur, tmax);
    float alpha = __expf(m_cur - m_new);

    float psum = 0.f;
#pragma unroll
    for (int i = 0; i < 4; i++) {
      us4 pv;
      u16* pp = (u16*)&pv;
#pragma unroll
      for (int r = 0; r < 4; r++) {
        float pe = __expf(st[i][r] - m_new);
        psum += pe;
        pp[r] = f2bf(pe);
      }
      *(us4*)(&lP[w][l15 * 72 + i * 16 + quad * 4]) = pv;
    }
    psum += __shfl_xor(psum, 16);
    psum += __shfl_xor(psum, 32);
    l_sum = l_sum * alpha + psum;
    m_cur = m_new;

#pragma unroll
    for (int r = 0; r < 4; r++) {
      float ar = __shfl(alpha, quad * 4 + r);
#pragma unroll
      for (int j = 0; j < 8; j++) accO[j][r] *= ar;
    }

    bf16x8 pf[2];
#pragma unroll
    for (int ks = 0; ks < 2; ks++)
      pf[ks] = *(const bf16x8*)(&lP[w][l15 * 72 + ks * 32 + quad * 8]);
#pragma unroll
    for (int j = 0; j < 8; j++) {
      int d = j * 16 + l15;
#pragma unroll
      for (int ks = 0; ks < 2; ks++) {
        int lc = ks * 4 + quad;
        bf16x8 vf = *(const bf16x8*)(lV + d * 64 + ((lc ^ (d & 7)) * 8));
        accO[j] = __builtin_amdgcn_mfma_f32_16x16x32_bf16(pf[ks], vf, accO[j], 0, 0, 0);
      }
    }
    __syncthreads();
  }

  float linv = 1.0f / l_sum;
#pragma unroll
  for (int r = 0; r < 4; r++) {
    float lr = __shfl(linv, quad * 4 + r);
    int row = q0 + w * 16 + quad * 4 + r;
#pragma unroll
    for (int j = 0; j < 8; j++) {
      int col = h * HD + j * 16 + l15;
      ab[(size_t)row * HID + col] = f2bf(accO[j][r] * lr);
    }
  }
}

// ---------------- launch ----------------------------------------------------
extern "C" void kernel_launch(void* const* d_in, const int* in_sizes, int n_in,
                              void* d_out, int out_size, void* d_ws, size_t ws_size,
                              hipStream_t stream) {
  const float* x    = (const float*)d_in[0];
  const float* wq   = (const float*)d_in[1];
  const float* wk   = (const float*)d_in[2];
  const float* wv   = (const float*)d_in[3];
  const float* wo   = (const float*)d_in[4];
  const float* qnw  = (const float*)d_in[5];
  const float* knw  = (const float*)d_in[6];
  const float* cosT = (const float*)d_in[7];
  const float* sinT = (const float*)d_in[8];
  const int* positions = (const int*)d_in[11];

  static int attr_done = 0;
  if (!attr_done) {
    hipFuncSetAttribute((const void*)gemm_qkv8,
                        hipFuncAttributeMaxDynamicSharedMemorySize, 131072);
    hipFuncSetAttribute((const void*)gemm_out8,
                        hipFuncAttributeMaxDynamicSharedMemorySize, 131072);
    attr_done = 1;
  }

  char* ws = (char*)d_ws;
  u16* xb  = (u16*)(ws + 0ULL);          //  16 MB  x bf16
  u16* wqb = (u16*)(ws + 16777216ULL);   //  32 MB  wq bf16
  u16* wkb = (u16*)(ws + 50331648ULL);   //   8 MB  wk bf16
  u16* wvb = (u16*)(ws + 58720256ULL);   //   8 MB  wv bf16
  u16* wob = (u16*)(ws + 67108864ULL);   //  32 MB  wo bf16
  u16* Qp  = (u16*)(ws + 100663296ULL);  //  16 MB  q proj (S x 4096)
  u16* Kp  = (u16*)(ws + 117440512ULL);  //   4 MB  k proj (S x 1024)
  u16* vt  = (u16*)(ws + 121634816ULL);  //   4 MB  V^T (1024 x S)
  u16* qbh = (u16*)(ws + 125829120ULL);  //  16 MB  q heads (NH,S,D)
  u16* kbh = (u16*)(ws + 142606336ULL);  //   4 MB  k heads (KVH,S,D)
  u16* ab  = (u16*)(ws + 146800640ULL);  //  16 MB  attn out (S x 4096)
  float* O0 = (float*)(ws + 0ULL);         // 32 MB fp32 (aliases xb+wqb, dead)
  float* O1 = (float*)(ws + 33554432ULL);  // 32 MB fp32 (aliases wqb..wvb, dead)

  cvt_all<<<49152, 256, 0, stream>>>(x, wq, wk, wv, wo, xb, wqb, wkb, wvb, wob);

  gemm_qkv8<<<192, 512, 131072, stream>>>(xb, wqb, wkb, wvb, Qp, Kp, vt);

  rope_all<<<20480, 256, 0, stream>>>(Qp, Kp, qnw, knw, cosT, sinT, positions,
                                      qbh, kbh);

  attn_fwd<<<dim3(NH, S_LEN / 64), 256, 0, stream>>>(qbh, kbh, vt, ab);

  gemm_out8<<<256, 512, 131072, stream>>>(ab, wob, O0, O1);
  reduce_out<<<8192, 256, 0, stream>>>(O0, O1, (float*)d_out);
}

// Round 2
// 492.722 us; speedup vs baseline: 1.0944x; 1.0340x over previous
//
#include <hip/hip_runtime.h>

typedef unsigned short u16;
typedef unsigned int u32;
typedef __attribute__((ext_vector_type(8))) short bf16x8;
typedef __attribute__((ext_vector_type(4))) float f32x4;
struct __align__(8) us4 { u16 x, y, z, w; };

#define S_LEN 2048
#define HID   4096
#define NH    32
#define KVH   8
#define HD    128
#define MFMA16 __builtin_amdgcn_mfma_f32_16x16x32_bf16

__device__ inline u16 f2bf(float f) {
  u32 u = __float_as_uint(f);
  u32 r = (u + 0x7fffu + ((u >> 16) & 1u)) >> 16;  // RNE
  return (u16)r;
}
__device__ inline float bf2f(u16 h) { return __uint_as_float(((u32)h) << 16); }

__device__ inline void gld_lds16(const void* g, void* l) {
  __builtin_amdgcn_global_load_lds(
      (const __attribute__((address_space(1))) u32*)g,
      (__attribute__((address_space(3))) u32*)l, 16, 0, 0);
}

// ---------------- fused fp32 -> bf16 conversion (x, wq, wk, wv) -------------
// wo conversion moved into gemm_qkv8's 64 spare blocks (overlaps the GEMM).
__global__ __launch_bounds__(256)
void cvt_all(const float* __restrict__ x, const float* __restrict__ wq,
             const float* __restrict__ wk, const float* __restrict__ wv,
             u16* __restrict__ xb, u16* __restrict__ wqb,
             u16* __restrict__ wkb, u16* __restrict__ wvb) {
  int b = blockIdx.x;
  const float* in; u16* out; int base;
  if (b < 8192)       { in = x;  out = xb;  base = b; }
  else if (b < 24576) { in = wq; out = wqb; base = b - 8192; }
  else if (b < 28672) { in = wk; out = wkb; base = b - 24576; }
  else                { in = wv; out = wvb; base = b - 28672; }
  size_t i = ((size_t)base * 256 + threadIdx.x) * 4;
  f32x4 v = *(const f32x4*)(in + i);
  us4 o;
  o.x = f2bf(v[0]); o.y = f2bf(v[1]); o.z = f2bf(v[2]); o.w = f2bf(v[3]);
  *(us4*)(out + i) = o;
}

// ---------------- 256x256 / BK=64 8-phase deep-pipelined NT GEMM core -------
// 512 threads = 8 waves (2 M-half x 4 N-quarter). Per-wave C: 128x64.
// LDS (dynamic 128 KiB): A bufs [0,64K) = 2 x 256x64 bf16; B bufs [64K,128K).
// Half-tile slot = 128 rows x 64 cols = 16 KiB. Swizzle: 16B col-slot s of row
// r physically stored at s^(r&7) (write pre-swizzles the GLOBAL source; LDS
// dest stays linear for global_load_lds; read applies the same XOR).
//
// Consumption (all waves collectively): P0 reads ALL four slots of tile t
// (wr/wcn spread waves across both halves), so tile t+1 must be fully landed
// at the t -> t+1 boundary. Slot deadness: B slots die at P1.barrier2, A slots
// at P2.barrier2. Staging schedule (1.5-tile lookahead, min flight 5 phases):
//   t.P2: stage (t+2).B0,B1 -> this buf   (B dead since P1)
//   t.P3: stage (t+2).A0,A1 -> this buf   (A dead since P2)
//   boundary: s_waitcnt vmcnt(8) -> all of (t+1) landed; (t+2)'s 8 loads
//   remain in flight (issued 1-2 phases ago, needed 5-6 phases later).
__device__ __forceinline__ void stage_half(const u16* __restrict__ src, int ldk,
                                           int rowBase, int k0, char* lslot,
                                           int t) {
  int rl = t >> 3;
  int c8 = ((t & 7) ^ (rl & 7)) * 8;  // (r+64)&7 == r&7
  gld_lds16(src + (size_t)(rowBase + rl) * ldk + k0 + c8, lslot + t * 16);
  gld_lds16(src + (size_t)(rowBase + 64 + rl) * ldk + k0 + c8,
            lslot + 8192 + t * 16);
}

__device__ __forceinline__ void gemm256_core(
    const u16* __restrict__ A, const u16* __restrict__ W, int m0, int n0,
    int ldk, int kBeg, int kEnd, char* lds, f32x4 (&acc)[8][4]) {
  const int t = threadIdx.x;
  const int l = t & 63, w = t >> 6;
  const int l15 = l & 15, quad = l >> 4;
  const int wr = w >> 2, wcn = w & 3;
  const int nt = (kEnd - kBeg) >> 6;
  char* ldsA = lds;
  char* ldsB = lds + 65536;
  // fragment row ≡ l15 (mod 8) for every mIdx/n -> XOR term is frag-invariant
  const int swz0 = ((0 + quad) ^ (l15 & 7)) * 16;  // k-half 0
  const int swz1 = ((4 + quad) ^ (l15 & 7)) * 16;  // k-half 1
  const int aB0 = wr * 16384 + l15 * 128;
  const int bB0 = wcn * 8192 + l15 * 128;

#pragma unroll
  for (int m = 0; m < 8; m++)
#pragma unroll
    for (int n = 0; n < 4; n++) acc[m][n] = (f32x4){0.f, 0.f, 0.f, 0.f};

  // prologue: tiles 0 and 1 fully staged (16 loads); vmcnt(8) = tile 0 landed
  stage_half(W, ldk, n0,       kBeg, ldsB,         t);
  stage_half(W, ldk, n0 + 128, kBeg, ldsB + 16384, t);
  stage_half(A, ldk, m0,       kBeg, ldsA,         t);
  stage_half(A, ldk, m0 + 128, kBeg, ldsA + 16384, t);
  if (nt > 1) {
    stage_half(W, ldk, n0,       kBeg + 64, ldsB + 32768,         t);
    stage_half(W, ldk, n0 + 128, kBeg + 64, ldsB + 32768 + 16384, t);
    stage_half(A, ldk, m0,       kBeg + 64, ldsA + 32768,         t);
    stage_half(A, ldk, m0 + 128, kBeg + 64, ldsA + 32768 + 16384, t);
    asm volatile("s_waitcnt vmcnt(8)" ::: "memory");
  } else {
    asm volatile("s_waitcnt vmcnt(0)" ::: "memory");
  }
  __builtin_amdgcn_s_barrier();

  bf16x8 a[4][2], b[2][2], b2[2][2];
#pragma unroll 1
  for (int tt = 0; tt < nt; ++tt) {
    const int d = tt & 1;
    const int aO = d * 32768 + aB0;
    const int bO = d * 32768 + bB0;
    const int k2 = kBeg + (tt + 2) * 64;
    const bool pf = (tt + 2 < nt);

    // ---- phase 0 : Q00 = A0 x B0 ----
#pragma unroll
    for (int m = 0; m < 4; m++) {
      a[m][0] = *(const bf16x8*)(ldsA + aO + m * 2048 + swz0);
      a[m][1] = *(const bf16x8*)(ldsA + aO + m * 2048 + swz1);
    }
#pragma unroll
    for (int n = 0; n < 2; n++) {
      b[n][0] = *(const bf16x8*)(ldsB + bO + n * 2048 + swz0);
      b[n][1] = *(const bf16x8*)(ldsB + bO + n * 2048 + swz1);
    }
    __builtin_amdgcn_s_barrier();
    __builtin_amdgcn_s_setprio(1);
#pragma unroll
    for (int m = 0; m < 4; m++)
#pragma unroll
      for (int n = 0; n < 2; n++) {
        acc[m][n] = MFMA16(a[m][0], b[n][0], acc[m][n], 0, 0, 0);
        acc[m][n] = MFMA16(a[m][1], b[n][1], acc[m][n], 0, 0, 0);
      }
    __builtin_amdgcn_s_setprio(0);
    __builtin_amdgcn_s_barrier();

    // ---- phase 1 : Q01 = A0 x B1 ----
#pragma unroll
    for (int n = 0; n < 2; n++) {
      b2[n][0] = *(const bf16x8*)(ldsB + bO + (2 + n) * 2048 + swz0);
      b2[n][1] = *(const bf16x8*)(ldsB + bO + (2 + n) * 2048 + swz1);
    }
    __builtin_amdgcn_s_barrier();
    __builtin_amdgcn_s_setprio(1);
#pragma unroll
    for (int m = 0; m < 4; m++)
#pragma unroll
      for (int n = 0; n < 2; n++) {
        acc[m][2 + n] = MFMA16(a[m][0], b2[n][0], acc[m][2 + n], 0, 0, 0);
        acc[m][2 + n] = MFMA16(a[m][1], b2[n][1], acc[m][2 + n], 0, 0, 0);
      }
    __builtin_amdgcn_s_setprio(0);
    __builtin_amdgcn_s_barrier();

    // ---- phase 2 : Q10 = A1 x B0 ----  (stage next-next B: dead since P1)
    if (pf) {
      stage_half(W, ldk, n0,       k2, ldsB + d * 32768,         t);
      stage_half(W, ldk, n0 + 128, k2, ldsB + d * 32768 + 16384, t);
    }
#pragma unroll
    for (int m = 0; m < 4; m++) {
      a[m][0] = *(const bf16x8*)(ldsA + aO + (4 + m) * 2048 + swz0);
      a[m][1] = *(const bf16x8*)(ldsA + aO + (4 + m) * 2048 + swz1);
    }
    __builtin_amdgcn_s_barrier();
    __builtin_amdgcn_s_setprio(1);
#pragma unroll
    for (int m = 0; m < 4; m++)
#pragma unroll
      for (int n = 0; n < 2; n++) {
        acc[4 + m][n] = MFMA16(a[m][0], b[n][0], acc[4 + m][n], 0, 0, 0);
        acc[4 + m][n] = MFMA16(a[m][1], b[n][1], acc[4 + m][n], 0, 0, 0);
      }
    __builtin_amdgcn_s_setprio(0);
    __builtin_amdgcn_s_barrier();

    // ---- phase 3 : Q11 = A1 x B1 ----  (stage next-next A: dead since P2)
    if (pf) {
      stage_half(A, ldk, m0,       k2, ldsA + d * 32768,         t);
      stage_half(A, ldk, m0 + 128, k2, ldsA + d * 32768 + 16384, t);
    }
    __builtin_amdgcn_s_barrier();
    __builtin_amdgcn_s_setprio(1);
#pragma unroll
    for (int m = 0; m < 4; m++)
#pragma unroll
      for (int n = 0; n < 2; n++) {
        acc[4 + m][2 + n] = MFMA16(a[m][0], b2[n][0], acc[4 + m][2 + n], 0, 0, 0);
        acc[4 + m][2 + n] = MFMA16(a[m][1], b2[n][1], acc[4 + m][2 + n], 0, 0, 0);
      }
    __builtin_amdgcn_s_setprio(0);
    if (pf) asm volatile("s_waitcnt vmcnt(8)" ::: "memory");
    else    asm volatile("s_waitcnt vmcnt(0)" ::: "memory");
    __builtin_amdgcn_s_barrier();
  }
}

// ---------------- fused QKV projection (full K) + concurrent wo cvt ---------
__global__ __launch_bounds__(512, 2)
void gemm_qkv8(const u16* __restrict__ xb, const u16* __restrict__ wqb,
               const u16* __restrict__ wkb, const u16* __restrict__ wvb,
               u16* __restrict__ Qp, u16* __restrict__ Kp, u16* __restrict__ vt,
               const float* __restrict__ wo, u16* __restrict__ wob) {
  extern __shared__ char lds[];
  const int id = blockIdx.x;                 // 256 blocks: 192 GEMM + 64 cvt
  if (id >= 192) {                           // wo fp32->bf16 on spare CUs
    int cb = id - 192;
    size_t base = ((size_t)cb * 512 + threadIdx.x) * 4;
#pragma unroll 1
    for (int it = 0; it < 128; ++it) {
      size_t i = base + (size_t)it * 131072;
      f32x4 v = *(const f32x4*)(wo + i);
      us4 o;
      o.x = f2bf(v[0]); o.y = f2bf(v[1]); o.z = f2bf(v[2]); o.w = f2bf(v[3]);
      *(us4*)(wob + i) = o;
    }
    return;
  }
  const int sw = (id & 7) * 24 + (id >> 3);  // XCD-bijective swizzle
  const int bx = sw % 24, by = sw / 24;
  const u16* W; u16* C; int n0, ldc, epi;
  if (bx < 16)      { W = wqb; C = Qp; n0 = bx * 256;        ldc = HID;  epi = 0; }
  else if (bx < 20) { W = wkb; C = Kp; n0 = (bx - 16) * 256; ldc = 1024; epi = 0; }
  else              { W = wvb; C = vt; n0 = (bx - 20) * 256; ldc = 0;    epi = 1; }
  const int m0 = by * 256;

  f32x4 acc[8][4];
  gemm256_core(xb, W, m0, n0, HID, 0, HID, lds, acc);

  const int t = threadIdx.x, l = t & 63, w = t >> 6;
  const int l15 = l & 15, quad = l >> 4;
  const int wr = w >> 2, wcn = w & 3;
  if (epi == 0) {
#pragma unroll
    for (int m = 0; m < 8; m++) {
      int row0 = m0 + wr * 128 + m * 16 + quad * 4;
#pragma unroll
      for (int n = 0; n < 4; n++) {
        int col = n0 + wcn * 64 + n * 16 + l15;
#pragma unroll
        for (int r = 0; r < 4; r++)
          C[(size_t)(row0 + r) * ldc + col] = f2bf(acc[m][n][r]);
      }
    }
  } else {
#pragma unroll
    for (int m = 0; m < 8; m++) {
      int row0 = m0 + wr * 128 + m * 16 + quad * 4;
#pragma unroll
      for (int n = 0; n < 4; n++) {
        int col = n0 + wcn * 64 + n * 16 + l15;  // V row index (0..1023)
        us4 v;
        v.x = f2bf(acc[m][n][0]); v.y = f2bf(acc[m][n][1]);
        v.z = f2bf(acc[m][n][2]); v.w = f2bf(acc[m][n][3]);
        *(us4*)(vt + (size_t)col * S_LEN + row0) = v;  // transposed store
      }
    }
  }
}

// ---------------- output projection, split-K x2 (256 blocks = full pack) ----
__global__ __launch_bounds__(512, 2)
void gemm_out8(const u16* __restrict__ ab, const u16* __restrict__ wob,
               float* __restrict__ O0, float* __restrict__ O1) {
  extern __shared__ char lds[];
  const int id = blockIdx.x;                 // 256 blocks
  const int sw = (id & 7) * 32 + (id >> 3);
  const int z = sw >> 7, rem = sw & 127;
  const int by = rem >> 4, bx = rem & 15;
  float* Op = z ? O1 : O0;

  f32x4 acc[8][4];
  gemm256_core(ab, wob, by * 256, bx * 256, HID, z * 2048, z * 2048 + 2048, lds, acc);

  const int t = threadIdx.x, l = t & 63, w = t >> 6;
  const int l15 = l & 15, quad = l >> 4;
  const int wr = w >> 2, wcn = w & 3;
#pragma unroll
  for (int m = 0; m < 8; m++) {
    int row0 = by * 256 + wr * 128 + m * 16 + quad * 4;
#pragma unroll
    for (int n = 0; n < 4; n++) {
      int col = bx * 256 + wcn * 64 + n * 16 + l15;
#pragma unroll
      for (int r = 0; r < 4; r++)
        Op[(size_t)(row0 + r) * HID + col] = acc[m][n][r];
    }
  }
}

__global__ __launch_bounds__(256)
void reduce_out(const float* __restrict__ O0, const float* __restrict__ O1,
                float* __restrict__ outp) {
  size_t i = ((size_t)blockIdx.x * 256 + threadIdx.x) * 4;
  f32x4 a = *(const f32x4*)(O0 + i);
  f32x4 b = *(const f32x4*)(O1 + i);
  a[0] += b[0]; a[1] += b[1]; a[2] += b[2]; a[3] += b[3];
  *(f32x4*)(outp + i) = a;
}

// ---------------- RMSNorm + RoPE relayout (single-source, no partials) ------
__global__ __launch_bounds__(256)
void rope_all(const u16* __restrict__ Qp, const u16* __restrict__ Kp,
              const float* __restrict__ qnw, const float* __restrict__ knw,
              const float* __restrict__ cosT, const float* __restrict__ sinT,
              const int* __restrict__ pos, u16* __restrict__ qbh,
              u16* __restrict__ kbh) {
  const int b = blockIdx.x;
  const int t = threadIdx.x, w = t >> 6, l = t & 63;
  const u16* xr; const float* nw; u16* orow; int s;
  if (b < 16384) {       // Q: NH=32 heads
    int p = b * 4 + w;
    s = p >> 5; int h = p & 31;
    xr = Qp + (size_t)s * HID + h * HD;
    nw = qnw;
    orow = qbh + ((size_t)h * S_LEN + s) * HD;
  } else {               // K: KVH=8 heads
    int p = (b - 16384) * 4 + w;
    s = p >> 3; int h = p & 7;
    xr = Kp + (size_t)s * 1024 + h * HD;
    nw = knw;
    orow = kbh + ((size_t)h * S_LEN + s) * HD;
  }
  float x1 = bf2f(xr[l]);
  float x2 = bf2f(xr[l + 64]);
  float ss = x1 * x1 + x2 * x2;
#pragma unroll
  for (int m = 1; m < 64; m <<= 1) ss += __shfl_xor(ss, m);
  float rinv = rsqrtf(ss * (1.0f / 128.0f) + 1e-6f);
  float n1 = x1 * rinv * nw[l];
  float n2 = x2 * rinv * nw[l + 64];
  int ps = pos[s];
  float c1 = cosT[ps * HD + l], s1 = sinT[ps * HD + l];
  float c2 = cosT[ps * HD + l + 64], s2 = sinT[ps * HD + l + 64];
  float y1 = n1 * c1 - n2 * s1;
  float y2 = n2 * c2 + n1 * s2;
  orow[l] = f2bf(y1);
  orow[l + 64] = f2bf(y2);
}

// ---------------- causal GQA flash attention (unchanged) --------------------
__global__ __launch_bounds__(256)
void attn_fwd(const u16* __restrict__ qh, const u16* __restrict__ kbh,
              const u16* __restrict__ vth, u16* __restrict__ ab) {
  __shared__ __align__(16) u16 lK[64 * 128];
  __shared__ __align__(16) u16 lV[128 * 64];
  __shared__ __align__(16) u16 lP[4][16 * 72];
  const int t = threadIdx.x, w = t >> 6, l = t & 63;
  const int quad = l >> 4, l15 = l & 15;
  const int h = blockIdx.x;
  const int qt = 31 - blockIdx.y;   // heavy blocks first
  const int kvh = h >> 2;
  const int q0 = qt * 64;
  const int qrow = q0 + w * 16 + l15;

  bf16x8 qf[4];
#pragma unroll
  for (int ks = 0; ks < 4; ks++)
    qf[ks] = *(const bf16x8*)(qh + ((size_t)h * S_LEN + qrow) * HD + ks * 32 + quad * 8);

  f32x4 accO[8];
#pragma unroll
  for (int j = 0; j < 8; j++) accO[j] = (f32x4){0.f, 0.f, 0.f, 0.f};
  float m_cur = -3.0e38f, l_sum = 0.f;
  const float scale = 0.08838834764831845f;

  const int ntiles = qt + 1;
  for (int tt = 0; tt < ntiles; tt++) {
    const int c0 = tt * 64;
#pragma unroll
    for (int i = 0; i < 4; i++) {
      int Cc = i * 256 + t;
      int r = Cc >> 4, ch = Cc & 15;
      int gch = ch ^ (r & 15);
      gld_lds16(kbh + ((size_t)kvh * S_LEN + c0 + r) * HD + gch * 8, lK + Cc * 8);
    }
#pragma unroll
    for (int i = 0; i < 4; i++) {
      int Cc = i * 256 + t;
      int d = Cc >> 3, ch = Cc & 7;
      int gch = ch ^ (d & 7);
      gld_lds16(vth + ((size_t)kvh * HD + d) * S_LEN + c0 + gch * 8, lV + Cc * 8);
    }
    __syncthreads();

    f32x4 st[4];
#pragma unroll
    for (int i = 0; i < 4; i++) {
      f32x4 sa = (f32x4){0.f, 0.f, 0.f, 0.f};
      int r = i * 16 + l15;
#pragma unroll
      for (int ks = 0; ks < 4; ks++) {
        int lc = ks * 4 + quad;
        bf16x8 kf = *(const bf16x8*)(lK + r * 128 + ((lc ^ (r & 15)) * 8));
        sa = __builtin_amdgcn_mfma_f32_16x16x32_bf16(kf, qf[ks], sa, 0, 0, 0);
      }
      st[i] = sa;
    }

    float tmax = -3.0e38f;
#pragma unroll
    for (int i = 0; i < 4; i++) {
#pragma unroll
      for (int r = 0; r < 4; r++) {
        int kcol = c0 + i * 16 + quad * 4 + r;
        float v = st[i][r] * scale;
        v = (kcol <= qrow) ? v : -3.0e38f;
        st[i][r] = v;
        tmax = fmaxf(tmax, v);
      }
    }
    tmax = fmaxf(tmax, __shfl_xor(tmax, 16));
    tmax = fmaxf(tmax, __shfl_xor(tmax, 32));
    float m_new = fmaxf(m_cur, tmax);
    float alpha = __expf(m_cur - m_new);

    float psum = 0.f;
#pragma unroll
    for (int i = 0; i < 4; i++) {
      us4 pv;
      u16* pp = (u16*)&pv;
#pragma unroll
      for (int r = 0; r < 4; r++) {
        float pe = __expf(st[i][r] - m_new);
        psum += pe;
        pp[r] = f2bf(pe);
      }
      *(us4*)(&lP[w][l15 * 72 + i * 16 + quad * 4]) = pv;
    }
    psum += __shfl_xor(psum, 16);
    psum += __shfl_xor(psum, 32);
    l_sum = l_sum * alpha + psum;
    m_cur = m_new;

#pragma unroll
    for (int r = 0; r < 4; r++) {
      float ar = __shfl(alpha, quad * 4 + r);
#pragma unroll
      for (int j = 0; j < 8; j++) accO[j][r] *= ar;
    }

    bf16x8 pf[2];
#pragma unroll
    for (int ks = 0; ks < 2; ks++)
      pf[ks] = *(const bf16x8*)(&lP[w][l15 * 72 + ks * 32 + quad * 8]);
#pragma unroll
    for (int j = 0; j < 8; j++) {
      int d = j * 16 + l15;
#pragma unroll
      for (int ks = 0; ks < 2; ks++) {
        int lc = ks * 4 + quad;
        bf16x8 vf = *(const bf16x8*)(lV + d * 64 + ((lc ^ (d & 7)) * 8));
        accO[j] = __builtin_amdgcn_mfma_f32_16x16x32_bf16(pf[ks], vf, accO[j], 0, 0, 0);
      }
    }
    __syncthreads();
  }

  float linv = 1.0f / l_sum;
#pragma unroll
  for (int r = 0; r < 4; r++) {
    float lr = __shfl(linv, quad * 4 + r);
    int row = q0 + w * 16 + quad * 4 + r;
#pragma unroll
    for (int j = 0; j < 8; j++) {
      int col = h * HD + j * 16 + l15;
      ab[(size_t)row * HID + col] = f2bf(accO[j][r] * lr);
    }
  }
}

// ---------------- launch ----------------------------------------------------
extern "C" void kernel_launch(void* const* d_in, const int* in_sizes, int n_in,
                              void* d_out, int out_size, void* d_ws, size_t ws_size,
                              hipStream_t stream) {
  const float* x    = (const float*)d_in[0];
  const float* wq   = (const float*)d_in[1];
  const float* wk   = (const float*)d_in[2];
  const float* wv   = (const float*)d_in[3];
  const float* wo   = (const float*)d_in[4];
  const float* qnw  = (const float*)d_in[5];
  const float* knw  = (const float*)d_in[6];
  const float* cosT = (const float*)d_in[7];
  const float* sinT = (const float*)d_in[8];
  const int* positions = (const int*)d_in[11];

  static int attr_done = 0;
  if (!attr_done) {
    hipFuncSetAttribute((const void*)gemm_qkv8,
                        hipFuncAttributeMaxDynamicSharedMemorySize, 131072);
    hipFuncSetAttribute((const void*)gemm_out8,
                        hipFuncAttributeMaxDynamicSharedMemorySize, 131072);
    attr_done = 1;
  }

  char* ws = (char*)d_ws;
  u16* xb  = (u16*)(ws + 0ULL);          //  16 MB  x bf16
  u16* wqb = (u16*)(ws + 16777216ULL);   //  32 MB  wq bf16
  u16* wkb = (u16*)(ws + 50331648ULL);   //   8 MB  wk bf16
  u16* wvb = (u16*)(ws + 58720256ULL);   //   8 MB  wv bf16
  u16* wob = (u16*)(ws + 67108864ULL);   //  32 MB  wo bf16
  u16* Qp  = (u16*)(ws + 100663296ULL);  //  16 MB  q proj (S x 4096)
  u16* Kp  = (u16*)(ws + 117440512ULL);  //   4 MB  k proj (S x 1024)
  u16* vt  = (u16*)(ws + 121634816ULL);  //   4 MB  V^T (1024 x S)
  u16* qbh = (u16*)(ws + 125829120ULL);  //  16 MB  q heads (NH,S,D)
  u16* kbh = (u16*)(ws + 142606336ULL);  //   4 MB  k heads (KVH,S,D)
  u16* ab  = (u16*)(ws + 146800640ULL);  //  16 MB  attn out (S x 4096)
  float* O0 = (float*)(ws + 0ULL);         // 32 MB fp32 (aliases xb+wqb, dead)
  float* O1 = (float*)(ws + 33554432ULL);  // 32 MB fp32 (aliases wqb..wvb, dead)

  cvt_all<<<32768, 256, 0, stream>>>(x, wq, wk, wv, xb, wqb, wkb, wvb);

  gemm_qkv8<<<256, 512, 131072, stream>>>(xb, wqb, wkb, wvb, Qp, Kp, vt, wo, wob);

  rope_all<<<20480, 256, 0, stream>>>(Qp, Kp, qnw, knw, cosT, sinT, positions,
                                      qbh, kbh);

  attn_fwd<<<dim3(NH, S_LEN / 64), 256, 0, stream>>>(qbh, kbh, vt, ab);

  gemm_out8<<<256, 512, 131072, stream>>>(ab, wob, O0, O1);
  reduce_out<<<8192, 256, 0, stream>>>(O0, O1, (float*)d_out);
}

// Round 3
// 491.781 us; speedup vs baseline: 1.0965x; 1.0019x over previous
//
#include <hip/hip_runtime.h>

typedef unsigned short u16;
typedef unsigned int u32;
typedef __attribute__((ext_vector_type(8))) short bf16x8;
typedef __attribute__((ext_vector_type(4))) float f32x4;
struct __align__(8) us4 { u16 x, y, z, w; };

#define S_LEN 2048
#define HID   4096
#define NH    32
#define KVH   8
#define HD    128
#define MFMA16 __builtin_amdgcn_mfma_f32_16x16x32_bf16

__device__ inline u16 f2bf(float f) {
  u32 u = __float_as_uint(f);
  u32 r = (u + 0x7fffu + ((u >> 16) & 1u)) >> 16;  // RNE
  return (u16)r;
}
__device__ inline float bf2f(u16 h) { return __uint_as_float(((u32)h) << 16); }

__device__ inline void gld_lds16(const void* g, void* l) {
  __builtin_amdgcn_global_load_lds(
      (const __attribute__((address_space(1))) u32*)g,
      (__attribute__((address_space(3))) u32*)l, 16, 0, 0);
}

// ---------------- fused fp32 -> bf16 conversion (x + concat [wq;wk;wv]) -----
// wqkv laid out as one 6144x4096 bf16 matrix so the QKV GEMM can tile the
// full 6144-col output space with BN=192 (256 blocks = 1/CU exactly).
__global__ __launch_bounds__(256)
void cvt_all(const float* __restrict__ x, const float* __restrict__ wq,
             const float* __restrict__ wk, const float* __restrict__ wv,
             u16* __restrict__ xb, u16* __restrict__ wqkvb) {
  int b = blockIdx.x;
  const float* in; u16* out; int base;
  if (b < 8192)       { in = x;  out = xb;                    base = b; }
  else if (b < 24576) { in = wq; out = wqkvb;                 base = b - 8192; }
  else if (b < 28672) { in = wk; out = wqkvb + 16777216;      base = b - 24576; }
  else                { in = wv; out = wqkvb + 20971520;      base = b - 28672; }
  size_t i = ((size_t)base * 256 + threadIdx.x) * 4;
  f32x4 v = *(const f32x4*)(in + i);
  us4 o;
  o.x = f2bf(v[0]); o.y = f2bf(v[1]); o.z = f2bf(v[2]); o.w = f2bf(v[3]);
  *(us4*)(out + i) = o;
}

// 64-row x 64-col (8KB) staging slab: 512 threads x 16B, XOR-preswizzled src.
__device__ __forceinline__ void stage_slab(const u16* __restrict__ src, int ldk,
                                           int rowBase, int k0, char* lslot,
                                           int t) {
  int rl = t >> 3;
  int c8 = ((t & 7) ^ (rl & 7)) * 8;
  gld_lds16(src + (size_t)(rowBase + rl) * ldk + k0 + c8, lslot + t * 16);
}

// 128-row half-tile (two slabs) for the 256x256 core (gemm_out8).
__device__ __forceinline__ void stage_half(const u16* __restrict__ src, int ldk,
                                           int rowBase, int k0, char* lslot,
                                           int t) {
  int rl = t >> 3;
  int c8 = ((t & 7) ^ (rl & 7)) * 8;
  gld_lds16(src + (size_t)(rowBase + rl) * ldk + k0 + c8, lslot + t * 16);
  gld_lds16(src + (size_t)(rowBase + 64 + rl) * ldk + k0 + c8,
            lslot + 8192 + t * 16);
}

// ---------------- QKV GEMM: 256x192 tile, BK=64, 8 waves (4M x 2N) ----------
// 256 blocks (8 M x 32 N over the 2048 x 6144 output) = exactly 1 block/CU.
// LDS 112KB: A = 2 buf x 256x64 (32KB each) at [0,64K); B = 2 buf x 192x64
// (24KB each) at [64K,112K). Swizzle: 16B slot s of row r at s^(r&7).
// Phases per K-tile: P0 {a01,b012 reads | stage A(t+1) slabs01 | 12 MFMA}
//  P1 {b345 | A(t+1) slabs23 | 12}  P2 {a23 | stage B(t+2) | 12}  P3 {12}.
// A slots die at P2 (so A(t+1)->other buf from P0 ok); B slots die at P1
// (so B(t+2)->this buf at P2 ok). Boundary: vmcnt(3) = B(t+2) in flight.
__global__ __launch_bounds__(512, 2)
void gemm_qkv8(const u16* __restrict__ xb, const u16* __restrict__ wqkvb,
               u16* __restrict__ Qp, u16* __restrict__ Kp, u16* __restrict__ vt) {
  extern __shared__ char lds[];
  const int id = blockIdx.x;                 // 256 blocks, 256 % 8 == 0
  const int sw = (id & 7) * 32 + (id >> 3);  // XCD-bijective swizzle
  const int by = sw >> 5, bx = sw & 31;
  const int m0 = by * 256, n0 = bx * 192;
  const int t = threadIdx.x;
  const int l = t & 63, w = t >> 6;
  const int l15 = l & 15, quad = l >> 4;
  const int wr = w >> 1, wcn = w & 1;        // 4 M-strips x 2 N-strips
  char* ldsA = lds;
  char* ldsB = lds + 65536;
  const int swz0 = ((0 + quad) ^ (l15 & 7)) * 16;
  const int swz1 = ((4 + quad) ^ (l15 & 7)) * 16;
  const int aB0 = wr * 8192 + l15 * 128;     // 64-row strip
  const int bB0 = wcn * 12288 + l15 * 128;   // 96-row strip
  const int nt = HID / 64;

  f32x4 acc[4][6];
#pragma unroll
  for (int m = 0; m < 4; m++)
#pragma unroll
    for (int n = 0; n < 6; n++) acc[m][n] = (f32x4){0.f, 0.f, 0.f, 0.f};

  // prologue: B(0) A(0) B(1); vmcnt(3) leaves B(1)'s 3 loads in flight
#pragma unroll
  for (int s = 0; s < 3; s++) stage_slab(wqkvb, HID, n0 + s * 64, 0, ldsB + s * 8192, t);
#pragma unroll
  for (int s = 0; s < 4; s++) stage_slab(xb, HID, m0 + s * 64, 0, ldsA + s * 8192, t);
#pragma unroll
  for (int s = 0; s < 3; s++) stage_slab(wqkvb, HID, n0 + s * 64, 64, ldsB + 24576 + s * 8192, t);
  asm volatile("s_waitcnt vmcnt(3)" ::: "memory");
  __builtin_amdgcn_s_barrier();

  bf16x8 a[2][2], a2[2][2], b[3][2], b2[3][2];
#pragma unroll 1
  for (int tt = 0; tt < nt; ++tt) {
    const int d = tt & 1, dn = d ^ 1;
    const int aO = d * 32768 + aB0;
    const int bO = d * 24576 + bB0;
    const int k1 = (tt + 1) * 64, k2 = (tt + 2) * 64;
    const bool pf1 = (tt + 1 < nt), pf2 = (tt + 2 < nt);

    // ---- P0 : acc[0..1][0..2] ----
#pragma unroll
    for (int m = 0; m < 2; m++) {
      a[m][0] = *(const bf16x8*)(ldsA + aO + m * 2048 + swz0);
      a[m][1] = *(const bf16x8*)(ldsA + aO + m * 2048 + swz1);
    }
#pragma unroll
    for (int n = 0; n < 3; n++) {
      b[n][0] = *(const bf16x8*)(ldsB + bO + n * 2048 + swz0);
      b[n][1] = *(const bf16x8*)(ldsB + bO + n * 2048 + swz1);
    }
    if (pf1) {
      stage_slab(xb, HID, m0,      k1, ldsA + dn * 32768,        t);
      stage_slab(xb, HID, m0 + 64, k1, ldsA + dn * 32768 + 8192, t);
    }
    __builtin_amdgcn_s_barrier();
    __builtin_amdgcn_s_setprio(1);
#pragma unroll
    for (int m = 0; m < 2; m++)
#pragma unroll
      for (int n = 0; n < 3; n++) {
        acc[m][n] = MFMA16(a[m][0], b[n][0], acc[m][n], 0, 0, 0);
        acc[m][n] = MFMA16(a[m][1], b[n][1], acc[m][n], 0, 0, 0);
      }
    __builtin_amdgcn_s_setprio(0);
    __builtin_amdgcn_s_barrier();

    // ---- P1 : acc[0..1][3..5] ----
#pragma unroll
    for (int n = 0; n < 3; n++) {
      b2[n][0] = *(const bf16x8*)(ldsB + bO + (3 + n) * 2048 + swz0);
      b2[n][1] = *(const bf16x8*)(ldsB + bO + (3 + n) * 2048 + swz1);
    }
    if (pf1) {
      stage_slab(xb, HID, m0 + 128, k1, ldsA + dn * 32768 + 16384, t);
      stage_slab(xb, HID, m0 + 192, k1, ldsA + dn * 32768 + 24576, t);
    }
    __builtin_amdgcn_s_barrier();
    __builtin_amdgcn_s_setprio(1);
#pragma unroll
    for (int m = 0; m < 2; m++)
#pragma unroll
      for (int n = 0; n < 3; n++) {
        acc[m][3 + n] = MFMA16(a[m][0], b2[n][0], acc[m][3 + n], 0, 0, 0);
        acc[m][3 + n] = MFMA16(a[m][1], b2[n][1], acc[m][3 + n], 0, 0, 0);
      }
    __builtin_amdgcn_s_setprio(0);
    __builtin_amdgcn_s_barrier();

    // ---- P2 + P3 : acc[2..3][0..5] ----
#pragma unroll
    for (int m = 0; m < 2; m++) {
      a2[m][0] = *(const bf16x8*)(ldsA + aO + (2 + m) * 2048 + swz0);
      a2[m][1] = *(const bf16x8*)(ldsA + aO + (2 + m) * 2048 + swz1);
    }
    if (pf2) {
#pragma unroll
      for (int s = 0; s < 3; s++)
        stage_slab(wqkvb, HID, n0 + s * 64, k2, ldsB + d * 24576 + s * 8192, t);
    }
    __builtin_amdgcn_s_barrier();
    __builtin_amdgcn_s_setprio(1);
#pragma unroll
    for (int m = 0; m < 2; m++)
#pragma unroll
      for (int n = 0; n < 3; n++) {
        acc[2 + m][n] = MFMA16(a2[m][0], b[n][0], acc[2 + m][n], 0, 0, 0);
        acc[2 + m][n] = MFMA16(a2[m][1], b[n][1], acc[2 + m][n], 0, 0, 0);
      }
#pragma unroll
    for (int m = 0; m < 2; m++)
#pragma unroll
      for (int n = 0; n < 3; n++) {
        acc[2 + m][3 + n] = MFMA16(a2[m][0], b2[n][0], acc[2 + m][3 + n], 0, 0, 0);
        acc[2 + m][3 + n] = MFMA16(a2[m][1], b2[n][1], acc[2 + m][3 + n], 0, 0, 0);
      }
    __builtin_amdgcn_s_setprio(0);
    if (pf1) {
      if (pf2) asm volatile("s_waitcnt vmcnt(3)" ::: "memory");
      else     asm volatile("s_waitcnt vmcnt(0)" ::: "memory");
      __builtin_amdgcn_s_barrier();
    }
  }

  // epilogue: route 16-col groups to Qp / Kp / vt (boundaries 16-aligned ->
  // branch is wave-uniform per (m,n))
#pragma unroll
  for (int m = 0; m < 4; m++) {
    int row0 = m0 + wr * 64 + m * 16 + quad * 4;
#pragma unroll
    for (int n = 0; n < 6; n++) {
      int col = n0 + wcn * 96 + n * 16 + l15;
      if (col < 4096) {
#pragma unroll
        for (int r = 0; r < 4; r++)
          Qp[(size_t)(row0 + r) * HID + col] = f2bf(acc[m][n][r]);
      } else if (col < 5120) {
#pragma unroll
        for (int r = 0; r < 4; r++)
          Kp[(size_t)(row0 + r) * 1024 + (col - 4096)] = f2bf(acc[m][n][r]);
      } else {
        us4 v;
        v.x = f2bf(acc[m][n][0]); v.y = f2bf(acc[m][n][1]);
        v.z = f2bf(acc[m][n][2]); v.w = f2bf(acc[m][n][3]);
        *(us4*)(vt + (size_t)(col - 5120) * S_LEN + row0) = v;  // V^T store
      }
    }
  }
}

// ---------------- 256x256 / BK=64 core (used by gemm_out8) ------------------
__device__ __forceinline__ void gemm256_core(
    const u16* __restrict__ A, const u16* __restrict__ W, int m0, int n0,
    int ldk, int kBeg, int kEnd, char* lds, f32x4 (&acc)[8][4]) {
  const int t = threadIdx.x;
  const int l = t & 63, w = t >> 6;
  const int l15 = l & 15, quad = l >> 4;
  const int wr = w >> 2, wcn = w & 3;
  const int nt = (kEnd - kBeg) >> 6;
  char* ldsA = lds;
  char* ldsB = lds + 65536;
  const int swz0 = ((0 + quad) ^ (l15 & 7)) * 16;
  const int swz1 = ((4 + quad) ^ (l15 & 7)) * 16;
  const int aB0 = wr * 16384 + l15 * 128;
  const int bB0 = wcn * 8192 + l15 * 128;

#pragma unroll
  for (int m = 0; m < 8; m++)
#pragma unroll
    for (int n = 0; n < 4; n++) acc[m][n] = (f32x4){0.f, 0.f, 0.f, 0.f};

  stage_half(W, ldk, n0,       kBeg, ldsB,         t);
  stage_half(W, ldk, n0 + 128, kBeg, ldsB + 16384, t);
  stage_half(A, ldk, m0,       kBeg, ldsA,         t);
  stage_half(A, ldk, m0 + 128, kBeg, ldsA + 16384, t);
  if (nt > 1) {
    stage_half(W, ldk, n0,       kBeg + 64, ldsB + 32768,         t);
    stage_half(W, ldk, n0 + 128, kBeg + 64, ldsB + 32768 + 16384, t);
    stage_half(A, ldk, m0,       kBeg + 64, ldsA + 32768,         t);
    stage_half(A, ldk, m0 + 128, kBeg + 64, ldsA + 32768 + 16384, t);
    asm volatile("s_waitcnt vmcnt(8)" ::: "memory");
  } else {
    asm volatile("s_waitcnt vmcnt(0)" ::: "memory");
  }
  __builtin_amdgcn_s_barrier();

  bf16x8 a[4][2], b[2][2], b2[2][2];
#pragma unroll 1
  for (int tt = 0; tt < nt; ++tt) {
    const int d = tt & 1;
    const int aO = d * 32768 + aB0;
    const int bO = d * 32768 + bB0;
    const int k2 = kBeg + (tt + 2) * 64;
    const bool pf = (tt + 2 < nt);

#pragma unroll
    for (int m = 0; m < 4; m++) {
      a[m][0] = *(const bf16x8*)(ldsA + aO + m * 2048 + swz0);
      a[m][1] = *(const bf16x8*)(ldsA + aO + m * 2048 + swz1);
    }
#pragma unroll
    for (int n = 0; n < 2; n++) {
      b[n][0] = *(const bf16x8*)(ldsB + bO + n * 2048 + swz0);
      b[n][1] = *(const bf16x8*)(ldsB + bO + n * 2048 + swz1);
    }
    __builtin_amdgcn_s_barrier();
    __builtin_amdgcn_s_setprio(1);
#pragma unroll
    for (int m = 0; m < 4; m++)
#pragma unroll
      for (int n = 0; n < 2; n++) {
        acc[m][n] = MFMA16(a[m][0], b[n][0], acc[m][n], 0, 0, 0);
        acc[m][n] = MFMA16(a[m][1], b[n][1], acc[m][n], 0, 0, 0);
      }
    __builtin_amdgcn_s_setprio(0);
    __builtin_amdgcn_s_barrier();

#pragma unroll
    for (int n = 0; n < 2; n++) {
      b2[n][0] = *(const bf16x8*)(ldsB + bO + (2 + n) * 2048 + swz0);
      b2[n][1] = *(const bf16x8*)(ldsB + bO + (2 + n) * 2048 + swz1);
    }
    __builtin_amdgcn_s_barrier();
    __builtin_amdgcn_s_setprio(1);
#pragma unroll
    for (int m = 0; m < 4; m++)
#pragma unroll
      for (int n = 0; n < 2; n++) {
        acc[m][2 + n] = MFMA16(a[m][0], b2[n][0], acc[m][2 + n], 0, 0, 0);
        acc[m][2 + n] = MFMA16(a[m][1], b2[n][1], acc[m][2 + n], 0, 0, 0);
      }
    __builtin_amdgcn_s_setprio(0);
    __builtin_amdgcn_s_barrier();

    if (pf) {
      stage_half(W, ldk, n0,       k2, ldsB + d * 32768,         t);
      stage_half(W, ldk, n0 + 128, k2, ldsB + d * 32768 + 16384, t);
    }
#pragma unroll
    for (int m = 0; m < 4; m++) {
      a[m][0] = *(const bf16x8*)(ldsA + aO + (4 + m) * 2048 + swz0);
      a[m][1] = *(const bf16x8*)(ldsA + aO + (4 + m) * 2048 + swz1);
    }
    __builtin_amdgcn_s_barrier();
    __builtin_amdgcn_s_setprio(1);
#pragma unroll
    for (int m = 0; m < 4; m++)
#pragma unroll
      for (int n = 0; n < 2; n++) {
        acc[4 + m][n] = MFMA16(a[m][0], b[n][0], acc[4 + m][n], 0, 0, 0);
        acc[4 + m][n] = MFMA16(a[m][1], b[n][1], acc[4 + m][n], 0, 0, 0);
      }
    __builtin_amdgcn_s_setprio(0);
    __builtin_amdgcn_s_barrier();

    if (pf) {
      stage_half(A, ldk, m0,       k2, ldsA + d * 32768,         t);
      stage_half(A, ldk, m0 + 128, k2, ldsA + d * 32768 + 16384, t);
    }
    __builtin_amdgcn_s_barrier();
    __builtin_amdgcn_s_setprio(1);
#pragma unroll
    for (int m = 0; m < 4; m++)
#pragma unroll
      for (int n = 0; n < 2; n++) {
        acc[4 + m][2 + n] = MFMA16(a[m][0], b2[n][0], acc[4 + m][2 + n], 0, 0, 0);
        acc[4 + m][2 + n] = MFMA16(a[m][1], b2[n][1], acc[4 + m][2 + n], 0, 0, 0);
      }
    __builtin_amdgcn_s_setprio(0);
    if (pf) asm volatile("s_waitcnt vmcnt(8)" ::: "memory");
    else    asm volatile("s_waitcnt vmcnt(0)" ::: "memory");
    __builtin_amdgcn_s_barrier();
  }
}

// ---------------- output projection, split-K x2 (256 blocks = full pack) ----
__global__ __launch_bounds__(512, 2)
void gemm_out8(const u16* __restrict__ ab, const u16* __restrict__ wob,
               float* __restrict__ O0, float* __restrict__ O1) {
  extern __shared__ char lds[];
  const int id = blockIdx.x;                 // 256 blocks
  const int sw = (id & 7) * 32 + (id >> 3);
  const int z = sw >> 7, rem = sw & 127;
  const int by = rem >> 4, bx = rem & 15;
  float* Op = z ? O1 : O0;

  f32x4 acc[8][4];
  gemm256_core(ab, wob, by * 256, bx * 256, HID, z * 2048, z * 2048 + 2048, lds, acc);

  const int t = threadIdx.x, l = t & 63, w = t >> 6;
  const int l15 = l & 15, quad = l >> 4;
  const int wr = w >> 2, wcn = w & 3;
#pragma unroll
  for (int m = 0; m < 8; m++) {
    int row0 = by * 256 + wr * 128 + m * 16 + quad * 4;
#pragma unroll
    for (int n = 0; n < 4; n++) {
      int col = bx * 256 + wcn * 64 + n * 16 + l15;
#pragma unroll
      for (int r = 0; r < 4; r++)
        Op[(size_t)(row0 + r) * HID + col] = acc[m][n][r];
    }
  }
}

__global__ __launch_bounds__(256)
void reduce_out(const float* __restrict__ O0, const float* __restrict__ O1,
                float* __restrict__ outp) {
  size_t i = ((size_t)blockIdx.x * 256 + threadIdx.x) * 4;
  f32x4 a = *(const f32x4*)(O0 + i);
  f32x4 b = *(const f32x4*)(O1 + i);
  a[0] += b[0]; a[1] += b[1]; a[2] += b[2]; a[3] += b[3];
  *(f32x4*)(outp + i) = a;
}

// ---------------- RMSNorm + RoPE relayout -----------------------------------
__global__ __launch_bounds__(256)
void rope_all(const u16* __restrict__ Qp, const u16* __restrict__ Kp,
              const float* __restrict__ qnw, const float* __restrict__ knw,
              const float* __restrict__ cosT, const float* __restrict__ sinT,
              const int* __restrict__ pos, u16* __restrict__ qbh,
              u16* __restrict__ kbh) {
  const int b = blockIdx.x;
  const int t = threadIdx.x, w = t >> 6, l = t & 63;
  const u16* xr; const float* nw; u16* orow; int s;
  if (b < 16384) {       // Q: NH=32 heads
    int p = b * 4 + w;
    s = p >> 5; int h = p & 31;
    xr = Qp + (size_t)s * HID + h * HD;
    nw = qnw;
    orow = qbh + ((size_t)h * S_LEN + s) * HD;
  } else {               // K: KVH=8 heads
    int p = (b - 16384) * 4 + w;
    s = p >> 3; int h = p & 7;
    xr = Kp + (size_t)s * 1024 + h * HD;
    nw = knw;
    orow = kbh + ((size_t)h * S_LEN + s) * HD;
  }
  float x1 = bf2f(xr[l]);
  float x2 = bf2f(xr[l + 64]);
  float ss = x1 * x1 + x2 * x2;
#pragma unroll
  for (int m = 1; m < 64; m <<= 1) ss += __shfl_xor(ss, m);
  float rinv = rsqrtf(ss * (1.0f / 128.0f) + 1e-6f);
  float n1 = x1 * rinv * nw[l];
  float n2 = x2 * rinv * nw[l + 64];
  int ps = pos[s];
  float c1 = cosT[ps * HD + l], s1 = sinT[ps * HD + l];
  float c2 = cosT[ps * HD + l + 64], s2 = sinT[ps * HD + l + 64];
  float y1 = n1 * c1 - n2 * s1;
  float y2 = n2 * c2 + n1 * s2;
  orow[l] = f2bf(y1);
  orow[l + 64] = f2bf(y2);
}

// ---------------- causal GQA flash attention + concurrent wo cvt ------------
__global__ __launch_bounds__(256)
void attn_fwd(const u16* __restrict__ qh, const u16* __restrict__ kbh,
              const u16* __restrict__ vth, u16* __restrict__ ab,
              const float* __restrict__ wo, u16* __restrict__ wob) {
  __shared__ __align__(16) u16 lK[64 * 128];
  __shared__ __align__(16) u16 lV[128 * 64];
  __shared__ __align__(16) u16 lP[4][16 * 72];
  const int t = threadIdx.x, w = t >> 6, l = t & 63;
  const int quad = l >> 4, l15 = l & 15;
  if (blockIdx.x >= NH) {   // wo fp32->bf16 on 384 extra blocks (fills tail)
    int cb = (blockIdx.x - NH) * 32 + blockIdx.y;
    for (size_t i = (size_t)cb * 256 + t; i < 4194304; i += 98304) {
      size_t j = i * 4;
      f32x4 v = *(const f32x4*)(wo + j);
      us4 o;
      o.x = f2bf(v[0]); o.y = f2bf(v[1]); o.z = f2bf(v[2]); o.w = f2bf(v[3]);
      *(us4*)(wob + j) = o;
    }
    return;
  }
  const int h = blockIdx.x;
  const int qt = 31 - blockIdx.y;   // heavy blocks first
  const int kvh = h >> 2;
  const int q0 = qt * 64;
  const int qrow = q0 + w * 16 + l15;

  bf16x8 qf[4];
#pragma unroll
  for (int ks = 0; ks < 4; ks++)
    qf[ks] = *(const bf16x8*)(qh + ((size_t)h * S_LEN + qrow) * HD + ks * 32 + quad * 8);

  f32x4 accO[8];
#pragma unroll
  for (int j = 0; j < 8; j++) accO[j] = (f32x4){0.f, 0.f, 0.f, 0.f};
  float m_cur = -3.0e38f, l_sum = 0.f;
  const float scale = 0.08838834764831845f;

  const int ntiles = qt + 1;
  for (int tt = 0; tt < ntiles; tt++) {
    const int c0 = tt * 64;
#pragma unroll
    for (int i = 0; i < 4; i++) {
      int Cc = i * 256 + t;
      int r = Cc >> 4, ch = Cc & 15;
      int gch = ch ^ (r & 15);
      gld_lds16(kbh + ((size_t)kvh * S_LEN + c0 + r) * HD + gch * 8, lK + Cc * 8);
    }
#pragma unroll
    for (int i = 0; i < 4; i++) {
      int Cc = i * 256 + t;
      int d = Cc >> 3, ch = Cc & 7;
      int gch = ch ^ (d & 7);
      gld_lds16(vth + ((size_t)kvh * HD + d) * S_LEN + c0 + gch * 8, lV + Cc * 8);
    }
    __syncthreads();

    f32x4 st[4];
#pragma unroll
    for (int i = 0; i < 4; i++) {
      f32x4 sa = (f32x4){0.f, 0.f, 0.f, 0.f};
      int r = i * 16 + l15;
#pragma unroll
      for (int ks = 0; ks < 4; ks++) {
        int lc = ks * 4 + quad;
        bf16x8 kf = *(const bf16x8*)(lK + r * 128 + ((lc ^ (r & 15)) * 8));
        sa = __builtin_amdgcn_mfma_f32_16x16x32_bf16(kf, qf[ks], sa, 0, 0, 0);
      }
      st[i] = sa;
    }

    float tmax = -3.0e38f;
#pragma unroll
    for (int i = 0; i < 4; i++) {
#pragma unroll
      for (int r = 0; r < 4; r++) {
        int kcol = c0 + i * 16 + quad * 4 + r;
        float v = st[i][r] * scale;
        v = (kcol <= qrow) ? v : -3.0e38f;
        st[i][r] = v;
        tmax = fmaxf(tmax, v);
      }
    }
    tmax = fmaxf(tmax, __shfl_xor(tmax, 16));
    tmax = fmaxf(tmax, __shfl_xor(tmax, 32));
    float m_new = fmaxf(m_cur, tmax);
    float alpha = __expf(m_cur - m_new);

    float psum = 0.f;
#pragma unroll
    for (int i = 0; i < 4; i++) {
      us4 pv;
      u16* pp = (u16*)&pv;
#pragma unroll
      for (int r = 0; r < 4; r++) {
        float pe = __expf(st[i][r] - m_new);
        psum += pe;
        pp[r] = f2bf(pe);
      }
      *(us4*)(&lP[w][l15 * 72 + i * 16 + quad * 4]) = pv;
    }
    psum += __shfl_xor(psum, 16);
    psum += __shfl_xor(psum, 32);
    l_sum = l_sum * alpha + psum;
    m_cur = m_new;

#pragma unroll
    for (int r = 0; r < 4; r++) {
      float ar = __shfl(alpha, quad * 4 + r);
#pragma unroll
      for (int j = 0; j < 8; j++) accO[j][r] *= ar;
    }

    bf16x8 pf[2];
#pragma unroll
    for (int ks = 0; ks < 2; ks++)
      pf[ks] = *(const bf16x8*)(&lP[w][l15 * 72 + ks * 32 + quad * 8]);
#pragma unroll
    for (int j = 0; j < 8; j++) {
      int d = j * 16 + l15;
#pragma unroll
      for (int ks = 0; ks < 2; ks++) {
        int lc = ks * 4 + quad;
        bf16x8 vf = *(const bf16x8*)(lV + d * 64 + ((lc ^ (d & 7)) * 8));
        accO[j] = __builtin_amdgcn_mfma_f32_16x16x32_bf16(pf[ks], vf, accO[j], 0, 0, 0);
      }
    }
    __syncthreads();
  }

  float linv = 1.0f / l_sum;
#pragma unroll
  for (int r = 0; r < 4; r++) {
    float lr = __shfl(linv, quad * 4 + r);
    int row = q0 + w * 16 + quad * 4 + r;
#pragma unroll
    for (int j = 0; j < 8; j++) {
      int col = h * HD + j * 16 + l15;
      ab[(size_t)row * HID + col] = f2bf(accO[j][r] * lr);
    }
  }
}

// ---------------- launch ----------------------------------------------------
extern "C" void kernel_launch(void* const* d_in, const int* in_sizes, int n_in,
                              void* d_out, int out_size, void* d_ws, size_t ws_size,
                              hipStream_t stream) {
  const float* x    = (const float*)d_in[0];
  const float* wq   = (const float*)d_in[1];
  const float* wk   = (const float*)d_in[2];
  const float* wv   = (const float*)d_in[3];
  const float* wo   = (const float*)d_in[4];
  const float* qnw  = (const float*)d_in[5];
  const float* knw  = (const float*)d_in[6];
  const float* cosT = (const float*)d_in[7];
  const float* sinT = (const float*)d_in[8];
  const int* positions = (const int*)d_in[11];

  static int attr_done = 0;
  if (!attr_done) {
    hipFuncSetAttribute((const void*)gemm_qkv8,
                        hipFuncAttributeMaxDynamicSharedMemorySize, 114688);
    hipFuncSetAttribute((const void*)gemm_out8,
                        hipFuncAttributeMaxDynamicSharedMemorySize, 131072);
    attr_done = 1;
  }

  char* ws = (char*)d_ws;
  u16* xb    = (u16*)(ws + 0ULL);          //  16 MB  x bf16
  u16* wqkvb = (u16*)(ws + 16777216ULL);   //  48 MB  [wq;wk;wv] bf16 (6144x4096)
  u16* wob   = (u16*)(ws + 67108864ULL);   //  32 MB  wo bf16
  u16* Qp    = (u16*)(ws + 100663296ULL);  //  16 MB  q proj (S x 4096)
  u16* Kp    = (u16*)(ws + 117440512ULL);  //   4 MB  k proj (S x 1024)
  u16* vt    = (u16*)(ws + 121634816ULL);  //   4 MB  V^T (1024 x S)
  u16* qbh   = (u16*)(ws + 125829120ULL);  //  16 MB  q heads (NH,S,D)
  u16* kbh   = (u16*)(ws + 142606336ULL);  //   4 MB  k heads (KVH,S,D)
  u16* ab    = (u16*)(ws + 146800640ULL);  //  16 MB  attn out (S x 4096)
  float* O0  = (float*)(ws + 0ULL);          // 32 MB fp32 (aliases xb+wqkvb head, dead)
  float* O1  = (float*)(ws + 33554432ULL);   // 32 MB fp32 (aliases wqkvb tail, dead)

  cvt_all<<<32768, 256, 0, stream>>>(x, wq, wk, wv, xb, wqkvb);

  gemm_qkv8<<<256, 512, 114688, stream>>>(xb, wqkvb, Qp, Kp, vt);

  rope_all<<<20480, 256, 0, stream>>>(Qp, Kp, qnw, knw, cosT, sinT, positions,
                                      qbh, kbh);

  attn_fwd<<<dim3(NH + 12, S_LEN / 64), 256, 0, stream>>>(qbh, kbh, vt, ab,
                                                          wo, wob);

  gemm_out8<<<256, 512, 131072, stream>>>(ab, wob, O0, O1);
  reduce_out<<<8192, 256, 0, stream>>>(O0, O1, (float*)d_out);
}

// Round 4
// 483.845 us; speedup vs baseline: 1.1144x; 1.0164x over previous
//
#include <hip/hip_runtime.h>

typedef unsigned short u16;
typedef unsigned int u32;
typedef __attribute__((ext_vector_type(8))) short bf16x8;
typedef __attribute__((ext_vector_type(4))) float f32x4;
struct __align__(8) us4 { u16 x, y, z, w; };

#define S_LEN 2048
#define HID   4096
#define NH    32
#define KVH   8
#define HD    128
#define MFMA16 __builtin_amdgcn_mfma_f32_16x16x32_bf16

__device__ inline u16 f2bf(float f) {
  u32 u = __float_as_uint(f);
  u32 r = (u + 0x7fffu + ((u >> 16) & 1u)) >> 16;  // RNE
  return (u16)r;
}
__device__ inline float bf2f(u16 h) { return __uint_as_float(((u32)h) << 16); }

__device__ inline void gld_lds16(const void* g, void* l) {
  __builtin_amdgcn_global_load_lds(
      (const __attribute__((address_space(1))) u32*)g,
      (__attribute__((address_space(3))) u32*)l, 16, 0, 0);
}

// ---------------- fused fp32 -> bf16 conversion (x + concat [wq;wk;wv]) -----
__global__ __launch_bounds__(256)
void cvt_all(const float* __restrict__ x, const float* __restrict__ wq,
             const float* __restrict__ wk, const float* __restrict__ wv,
             u16* __restrict__ xb, u16* __restrict__ wqkvb) {
  int b = blockIdx.x;
  const float* in; u16* out; int base;
  if (b < 8192)       { in = x;  out = xb;                    base = b; }
  else if (b < 24576) { in = wq; out = wqkvb;                 base = b - 8192; }
  else if (b < 28672) { in = wk; out = wqkvb + 16777216;      base = b - 24576; }
  else                { in = wv; out = wqkvb + 20971520;      base = b - 28672; }
  size_t i = ((size_t)base * 256 + threadIdx.x) * 4;
  f32x4 v = *(const f32x4*)(in + i);
  us4 o;
  o.x = f2bf(v[0]); o.y = f2bf(v[1]); o.z = f2bf(v[2]); o.w = f2bf(v[3]);
  *(us4*)(out + i) = o;
}

// 64-row x 64-col (8KB) staging slab: 512 threads x 16B, XOR-preswizzled src.
__device__ __forceinline__ void stage_slab(const u16* __restrict__ src, int ldk,
                                           int rowBase, int k0, char* lslot,
                                           int t) {
  int rl = t >> 3;
  int c8 = ((t & 7) ^ (rl & 7)) * 8;
  gld_lds16(src + (size_t)(rowBase + rl) * ldk + k0 + c8, lslot + t * 16);
}

// ---------------- QKV GEMM: 256x192 tile, BK=64, 8 waves (4M x 2N) ----------
// 256 blocks (8 M x 32 N over 2048 x 6144) = exactly 1 block/CU. (unchanged)
__global__ __launch_bounds__(512, 2)
void gemm_qkv8(const u16* __restrict__ xb, const u16* __restrict__ wqkvb,
               u16* __restrict__ Qp, u16* __restrict__ Kp, u16* __restrict__ vt) {
  extern __shared__ char lds[];
  const int id = blockIdx.x;
  const int sw = (id & 7) * 32 + (id >> 3);  // XCD-bijective swizzle
  const int by = sw >> 5, bx = sw & 31;
  const int m0 = by * 256, n0 = bx * 192;
  const int t = threadIdx.x;
  const int l = t & 63, w = t >> 6;
  const int l15 = l & 15, quad = l >> 4;
  const int wr = w >> 1, wcn = w & 1;
  char* ldsA = lds;
  char* ldsB = lds + 65536;
  const int swz0 = ((0 + quad) ^ (l15 & 7)) * 16;
  const int swz1 = ((4 + quad) ^ (l15 & 7)) * 16;
  const int aB0 = wr * 8192 + l15 * 128;
  const int bB0 = wcn * 12288 + l15 * 128;
  const int nt = HID / 64;

  f32x4 acc[4][6];
#pragma unroll
  for (int m = 0; m < 4; m++)
#pragma unroll
    for (int n = 0; n < 6; n++) acc[m][n] = (f32x4){0.f, 0.f, 0.f, 0.f};

#pragma unroll
  for (int s = 0; s < 3; s++) stage_slab(wqkvb, HID, n0 + s * 64, 0, ldsB + s * 8192, t);
#pragma unroll
  for (int s = 0; s < 4; s++) stage_slab(xb, HID, m0 + s * 64, 0, ldsA + s * 8192, t);
#pragma unroll
  for (int s = 0; s < 3; s++) stage_slab(wqkvb, HID, n0 + s * 64, 64, ldsB + 24576 + s * 8192, t);
  asm volatile("s_waitcnt vmcnt(3)" ::: "memory");
  __builtin_amdgcn_s_barrier();

  bf16x8 a[2][2], a2[2][2], b[3][2], b2[3][2];
#pragma unroll 1
  for (int tt = 0; tt < nt; ++tt) {
    const int d = tt & 1, dn = d ^ 1;
    const int aO = d * 32768 + aB0;
    const int bO = d * 24576 + bB0;
    const int k1 = (tt + 1) * 64, k2 = (tt + 2) * 64;
    const bool pf1 = (tt + 1 < nt), pf2 = (tt + 2 < nt);

    // ---- P0 ----
#pragma unroll
    for (int m = 0; m < 2; m++) {
      a[m][0] = *(const bf16x8*)(ldsA + aO + m * 2048 + swz0);
      a[m][1] = *(const bf16x8*)(ldsA + aO + m * 2048 + swz1);
    }
#pragma unroll
    for (int n = 0; n < 3; n++) {
      b[n][0] = *(const bf16x8*)(ldsB + bO + n * 2048 + swz0);
      b[n][1] = *(const bf16x8*)(ldsB + bO + n * 2048 + swz1);
    }
    if (pf1) {
      stage_slab(xb, HID, m0,      k1, ldsA + dn * 32768,        t);
      stage_slab(xb, HID, m0 + 64, k1, ldsA + dn * 32768 + 8192, t);
    }
    __builtin_amdgcn_s_barrier();
    __builtin_amdgcn_s_setprio(1);
#pragma unroll
    for (int m = 0; m < 2; m++)
#pragma unroll
      for (int n = 0; n < 3; n++) {
        acc[m][n] = MFMA16(a[m][0], b[n][0], acc[m][n], 0, 0, 0);
        acc[m][n] = MFMA16(a[m][1], b[n][1], acc[m][n], 0, 0, 0);
      }
    __builtin_amdgcn_s_setprio(0);
    __builtin_amdgcn_s_barrier();

    // ---- P1 ----
#pragma unroll
    for (int n = 0; n < 3; n++) {
      b2[n][0] = *(const bf16x8*)(ldsB + bO + (3 + n) * 2048 + swz0);
      b2[n][1] = *(const bf16x8*)(ldsB + bO + (3 + n) * 2048 + swz1);
    }
    if (pf1) {
      stage_slab(xb, HID, m0 + 128, k1, ldsA + dn * 32768 + 16384, t);
      stage_slab(xb, HID, m0 + 192, k1, ldsA + dn * 32768 + 24576, t);
    }
    __builtin_amdgcn_s_barrier();
    __builtin_amdgcn_s_setprio(1);
#pragma unroll
    for (int m = 0; m < 2; m++)
#pragma unroll
      for (int n = 0; n < 3; n++) {
        acc[m][3 + n] = MFMA16(a[m][0], b2[n][0], acc[m][3 + n], 0, 0, 0);
        acc[m][3 + n] = MFMA16(a[m][1], b2[n][1], acc[m][3 + n], 0, 0, 0);
      }
    __builtin_amdgcn_s_setprio(0);
    __builtin_amdgcn_s_barrier();

    // ---- P2 + P3 ----
#pragma unroll
    for (int m = 0; m < 2; m++) {
      a2[m][0] = *(const bf16x8*)(ldsA + aO + (2 + m) * 2048 + swz0);
      a2[m][1] = *(const bf16x8*)(ldsA + aO + (2 + m) * 2048 + swz1);
    }
    if (pf2) {
#pragma unroll
      for (int s = 0; s < 3; s++)
        stage_slab(wqkvb, HID, n0 + s * 64, k2, ldsB + d * 24576 + s * 8192, t);
    }
    __builtin_amdgcn_s_barrier();
    __builtin_amdgcn_s_setprio(1);
#pragma unroll
    for (int m = 0; m < 2; m++)
#pragma unroll
      for (int n = 0; n < 3; n++) {
        acc[2 + m][n] = MFMA16(a2[m][0], b[n][0], acc[2 + m][n], 0, 0, 0);
        acc[2 + m][n] = MFMA16(a2[m][1], b[n][1], acc[2 + m][n], 0, 0, 0);
      }
#pragma unroll
    for (int m = 0; m < 2; m++)
#pragma unroll
      for (int n = 0; n < 3; n++) {
        acc[2 + m][3 + n] = MFMA16(a2[m][0], b2[n][0], acc[2 + m][3 + n], 0, 0, 0);
        acc[2 + m][3 + n] = MFMA16(a2[m][1], b2[n][1], acc[2 + m][3 + n], 0, 0, 0);
      }
    __builtin_amdgcn_s_setprio(0);
    if (pf1) {
      if (pf2) asm volatile("s_waitcnt vmcnt(3)" ::: "memory");
      else     asm volatile("s_waitcnt vmcnt(0)" ::: "memory");
      __builtin_amdgcn_s_barrier();
    }
  }

#pragma unroll
  for (int m = 0; m < 4; m++) {
    int row0 = m0 + wr * 64 + m * 16 + quad * 4;
#pragma unroll
    for (int n = 0; n < 6; n++) {
      int col = n0 + wcn * 96 + n * 16 + l15;
      if (col < 4096) {
#pragma unroll
        for (int r = 0; r < 4; r++)
          Qp[(size_t)(row0 + r) * HID + col] = f2bf(acc[m][n][r]);
      } else if (col < 5120) {
#pragma unroll
        for (int r = 0; r < 4; r++)
          Kp[(size_t)(row0 + r) * 1024 + (col - 4096)] = f2bf(acc[m][n][r]);
      } else {
        us4 v;
        v.x = f2bf(acc[m][n][0]); v.y = f2bf(acc[m][n][1]);
        v.z = f2bf(acc[m][n][2]); v.w = f2bf(acc[m][n][3]);
        *(us4*)(vt + (size_t)(col - 5120) * S_LEN + row0) = v;  // V^T store
      }
    }
  }
}

// ---------------- output projection: 256x128 tile, full K, fp32 out --------
// 256 blocks (8 M x 32 N) = 1/CU; no split-K -> no reduce pass, no fp32
// partial round-trip. LDS 96KB: A 2x32KB [0,64K); B 2x16KB [64K,96K).
// Phases: P0 {a01,b01 | stage A(t+1)s01 | 8 MFMA}, P1 {b23 | A(t+1)s23 | 8},
// P2 {a23 | stage B(t+2)s01 | 16}. Boundary vmcnt(2) = B(t+2) in flight.
__global__ __launch_bounds__(512, 2)
void gemm_outF(const u16* __restrict__ ab, const u16* __restrict__ wob,
               float* __restrict__ outp) {
  extern __shared__ char lds[];
  const int id = blockIdx.x;                 // 256 blocks
  const int sw = (id & 7) * 32 + (id >> 3);
  const int by = sw >> 5, bx = sw & 31;
  const int m0 = by * 256, n0 = bx * 128;
  const int t = threadIdx.x;
  const int l = t & 63, w = t >> 6;
  const int l15 = l & 15, quad = l >> 4;
  const int wr = w >> 1, wcn = w & 1;        // 4 M-strips x 2 N-strips (64x64)
  char* ldsA = lds;
  char* ldsB = lds + 65536;
  const int swz0 = ((0 + quad) ^ (l15 & 7)) * 16;
  const int swz1 = ((4 + quad) ^ (l15 & 7)) * 16;
  const int aB0 = wr * 8192 + l15 * 128;
  const int bB0 = wcn * 8192 + l15 * 128;
  const int nt = HID / 64;

  f32x4 acc[4][4];
#pragma unroll
  for (int m = 0; m < 4; m++)
#pragma unroll
    for (int n = 0; n < 4; n++) acc[m][n] = (f32x4){0.f, 0.f, 0.f, 0.f};

  // prologue: B(0), A(0), B(1); vmcnt(2) leaves B(1) in flight
  stage_slab(wob, HID, n0,      0, ldsB,        t);
  stage_slab(wob, HID, n0 + 64, 0, ldsB + 8192, t);
#pragma unroll
  for (int s = 0; s < 4; s++) stage_slab(ab, HID, m0 + s * 64, 0, ldsA + s * 8192, t);
  stage_slab(wob, HID, n0,      64, ldsB + 16384,        t);
  stage_slab(wob, HID, n0 + 64, 64, ldsB + 16384 + 8192, t);
  asm volatile("s_waitcnt vmcnt(2)" ::: "memory");
  __builtin_amdgcn_s_barrier();

  bf16x8 a[2][2], a2[2][2], b[2][2], b2[2][2];
#pragma unroll 1
  for (int tt = 0; tt < nt; ++tt) {
    const int d = tt & 1, dn = d ^ 1;
    const int aO = d * 32768 + aB0;
    const int bO = d * 16384 + bB0;
    const int k1 = (tt + 1) * 64, k2 = (tt + 2) * 64;
    const bool pf1 = (tt + 1 < nt), pf2 = (tt + 2 < nt);

    // ---- P0 : m01 x n01 ----
#pragma unroll
    for (int m = 0; m < 2; m++) {
      a[m][0] = *(const bf16x8*)(ldsA + aO + m * 2048 + swz0);
      a[m][1] = *(const bf16x8*)(ldsA + aO + m * 2048 + swz1);
    }
#pragma unroll
    for (int n = 0; n < 2; n++) {
      b[n][0] = *(const bf16x8*)(ldsB + bO + n * 2048 + swz0);
      b[n][1] = *(const bf16x8*)(ldsB + bO + n * 2048 + swz1);
    }
    if (pf1) {
      stage_slab(ab, HID, m0,      k1, ldsA + dn * 32768,        t);
      stage_slab(ab, HID, m0 + 64, k1, ldsA + dn * 32768 + 8192, t);
    }
    __builtin_amdgcn_s_barrier();
    __builtin_amdgcn_s_setprio(1);
#pragma unroll
    for (int m = 0; m < 2; m++)
#pragma unroll
      for (int n = 0; n < 2; n++) {
        acc[m][n] = MFMA16(a[m][0], b[n][0], acc[m][n], 0, 0, 0);
        acc[m][n] = MFMA16(a[m][1], b[n][1], acc[m][n], 0, 0, 0);
      }
    __builtin_amdgcn_s_setprio(0);
    __builtin_amdgcn_s_barrier();

    // ---- P1 : m01 x n23 ----
#pragma unroll
    for (int n = 0; n < 2; n++) {
      b2[n][0] = *(const bf16x8*)(ldsB + bO + (2 + n) * 2048 + swz0);
      b2[n][1] = *(const bf16x8*)(ldsB + bO + (2 + n) * 2048 + swz1);
    }
    if (pf1) {
      stage_slab(ab, HID, m0 + 128, k1, ldsA + dn * 32768 + 16384, t);
      stage_slab(ab, HID, m0 + 192, k1, ldsA + dn * 32768 + 24576, t);
    }
    __builtin_amdgcn_s_barrier();
    __builtin_amdgcn_s_setprio(1);
#pragma unroll
    for (int m = 0; m < 2; m++)
#pragma unroll
      for (int n = 0; n < 2; n++) {
        acc[m][2 + n] = MFMA16(a[m][0], b2[n][0], acc[m][2 + n], 0, 0, 0);
        acc[m][2 + n] = MFMA16(a[m][1], b2[n][1], acc[m][2 + n], 0, 0, 0);
      }
    __builtin_amdgcn_s_setprio(0);
    __builtin_amdgcn_s_barrier();

    // ---- P2 + P3 : m23 x all n ----
#pragma unroll
    for (int m = 0; m < 2; m++) {
      a2[m][0] = *(const bf16x8*)(ldsA + aO + (2 + m) * 2048 + swz0);
      a2[m][1] = *(const bf16x8*)(ldsA + aO + (2 + m) * 2048 + swz1);
    }
    if (pf2) {
      stage_slab(wob, HID, n0,      k2, ldsB + d * 16384,        t);
      stage_slab(wob, HID, n0 + 64, k2, ldsB + d * 16384 + 8192, t);
    }
    __builtin_amdgcn_s_barrier();
    __builtin_amdgcn_s_setprio(1);
#pragma unroll
    for (int m = 0; m < 2; m++)
#pragma unroll
      for (int n = 0; n < 2; n++) {
        acc[2 + m][n] = MFMA16(a2[m][0], b[n][0], acc[2 + m][n], 0, 0, 0);
        acc[2 + m][n] = MFMA16(a2[m][1], b[n][1], acc[2 + m][n], 0, 0, 0);
      }
#pragma unroll
    for (int m = 0; m < 2; m++)
#pragma unroll
      for (int n = 0; n < 2; n++) {
        acc[2 + m][2 + n] = MFMA16(a2[m][0], b2[n][0], acc[2 + m][2 + n], 0, 0, 0);
        acc[2 + m][2 + n] = MFMA16(a2[m][1], b2[n][1], acc[2 + m][2 + n], 0, 0, 0);
      }
    __builtin_amdgcn_s_setprio(0);
    if (pf1) {
      if (pf2) asm volatile("s_waitcnt vmcnt(2)" ::: "memory");
      else     asm volatile("s_waitcnt vmcnt(0)" ::: "memory");
      __builtin_amdgcn_s_barrier();
    }
  }

#pragma unroll
  for (int m = 0; m < 4; m++) {
    int row0 = m0 + wr * 64 + m * 16 + quad * 4;
#pragma unroll
    for (int n = 0; n < 4; n++) {
      int col = n0 + wcn * 64 + n * 16 + l15;
#pragma unroll
      for (int r = 0; r < 4; r++)
        outp[(size_t)(row0 + r) * HID + col] = acc[m][n][r];
    }
  }
}

// ---------------- RMSNorm + RoPE relayout (Q pre-scaled by 1/sqrt(d)) -------
__global__ __launch_bounds__(256)
void rope_all(const u16* __restrict__ Qp, const u16* __restrict__ Kp,
              const float* __restrict__ qnw, const float* __restrict__ knw,
              const float* __restrict__ cosT, const float* __restrict__ sinT,
              const int* __restrict__ pos, u16* __restrict__ qbh,
              u16* __restrict__ kbh) {
  const int b = blockIdx.x;
  const int t = threadIdx.x, w = t >> 6, l = t & 63;
  const u16* xr; const float* nw; u16* orow; int s;
  float sc;
  if (b < 16384) {       // Q: NH=32 heads
    int p = b * 4 + w;
    s = p >> 5; int h = p & 31;
    xr = Qp + (size_t)s * HID + h * HD;
    nw = qnw;
    orow = qbh + ((size_t)h * S_LEN + s) * HD;
    sc = 0.08838834764831845f;   // fold 1/sqrt(128) into Q
  } else {               // K: KVH=8 heads
    int p = (b - 16384) * 4 + w;
    s = p >> 3; int h = p & 7;
    xr = Kp + (size_t)s * 1024 + h * HD;
    nw = knw;
    orow = kbh + ((size_t)h * S_LEN + s) * HD;
    sc = 1.0f;
  }
  float x1 = bf2f(xr[l]);
  float x2 = bf2f(xr[l + 64]);
  float ss = x1 * x1 + x2 * x2;
#pragma unroll
  for (int m = 1; m < 64; m <<= 1) ss += __shfl_xor(ss, m);
  float rinv = rsqrtf(ss * (1.0f / 128.0f) + 1e-6f);
  float n1 = x1 * rinv * nw[l];
  float n2 = x2 * rinv * nw[l + 64];
  int ps = pos[s];
  float c1 = cosT[ps * HD + l], s1 = sinT[ps * HD + l];
  float c2 = cosT[ps * HD + l + 64], s2 = sinT[ps * HD + l + 64];
  float y1 = n1 * c1 - n2 * s1;
  float y2 = n2 * c2 + n1 * s2;
  orow[l] = f2bf(y1 * sc);
  orow[l + 64] = f2bf(y2 * sc);
}

// ---------------- causal GQA flash attention (double-buffered K/V) ----------
// LDS (dynamic 74752B): K 2x16KB [0,32K); V 2x16KB [32K,64K); P 9216B [64K,..)
// Tile t+1 stages during tile t's compute; counted vmcnt(8) across raw
// barriers (never 0 mid-loop). Mask only on the diagonal tile (Q pre-scaled).
// Defer-max: skip accO rescale when per-row max grew <= 8 (P bounded by e^8).
__global__ __launch_bounds__(256)
void attn_fwd(const u16* __restrict__ qh, const u16* __restrict__ kbh,
              const u16* __restrict__ vth, u16* __restrict__ ab,
              const float* __restrict__ wo, u16* __restrict__ wob) {
  extern __shared__ char alds[];
  const int t = threadIdx.x, w = t >> 6, l = t & 63;
  const int quad = l >> 4, l15 = l & 15;
  if (blockIdx.x >= NH) {   // wo fp32->bf16 on 384 extra blocks (fills tail)
    int cb = (blockIdx.x - NH) * 32 + blockIdx.y;
    for (size_t i = (size_t)cb * 256 + t; i < 4194304; i += 98304) {
      size_t j = i * 4;
      f32x4 v = *(const f32x4*)(wo + j);
      us4 o;
      o.x = f2bf(v[0]); o.y = f2bf(v[1]); o.z = f2bf(v[2]); o.w = f2bf(v[3]);
      *(us4*)(wob + j) = o;
    }
    return;
  }
  u16* lK = (u16*)alds;                    // + db*8192 (u16)
  u16* lV = (u16*)(alds + 32768);          // + db*8192
  u16* lP = (u16*)(alds + 65536) + w * 1152;
  const int h = blockIdx.x;
  const int qt = 31 - blockIdx.y;   // heavy blocks first
  const int kvh = h >> 2;
  const int q0 = qt * 64;
  const int qrow = q0 + w * 16 + l15;

  bf16x8 qf[4];
#pragma unroll
  for (int ks = 0; ks < 4; ks++)
    qf[ks] = *(const bf16x8*)(qh + ((size_t)h * S_LEN + qrow) * HD + ks * 32 + quad * 8);

  f32x4 accO[8];
#pragma unroll
  for (int j = 0; j < 8; j++) accO[j] = (f32x4){0.f, 0.f, 0.f, 0.f};
  float m_cur = -3.0e38f, l_sum = 0.f;

#define STAGE_KV(TT, DB)                                                      \
  do {                                                                        \
    int c0s = (TT) * 64;                                                      \
    _Pragma("unroll") for (int i = 0; i < 4; i++) {                           \
      int Cc = i * 256 + t;                                                   \
      int r = Cc >> 4, ch = Cc & 15;                                          \
      int gch = ch ^ (r & 15);                                                \
      gld_lds16(kbh + ((size_t)kvh * S_LEN + c0s + r) * HD + gch * 8,         \
                lK + (DB) * 8192 + Cc * 8);                                   \
    }                                                                         \
    _Pragma("unroll") for (int i = 0; i < 4; i++) {                           \
      int Cc = i * 256 + t;                                                   \
      int dd = Cc >> 3, ch = Cc & 7;                                          \
      int gch = ch ^ (dd & 7);                                                \
      gld_lds16(vth + ((size_t)kvh * HD + dd) * S_LEN + c0s + gch * 8,        \
                lV + (DB) * 8192 + Cc * 8);                                   \
    }                                                                         \
  } while (0)

  const int ntiles = qt + 1;
  STAGE_KV(0, 0);
  if (ntiles > 1) {
    STAGE_KV(1, 1);
    asm volatile("s_waitcnt vmcnt(8)" ::: "memory");
  } else {
    asm volatile("s_waitcnt vmcnt(0)" ::: "memory");
  }
  __builtin_amdgcn_s_barrier();

  for (int tt = 0; tt < ntiles; tt++) {
    const int db = tt & 1;
    const u16* lKd = lK + db * 8192;
    const u16* lVd = lV + db * 8192;

    f32x4 st[4];
#pragma unroll
    for (int i = 0; i < 4; i++) {
      f32x4 sa = (f32x4){0.f, 0.f, 0.f, 0.f};
      int r = i * 16 + l15;
#pragma unroll
      for (int ks = 0; ks < 4; ks++) {
        int lc = ks * 4 + quad;
        bf16x8 kf = *(const bf16x8*)(lKd + r * 128 + ((lc ^ (r & 15)) * 8));
        sa = MFMA16(kf, qf[ks], sa, 0, 0, 0);
      }
      st[i] = sa;
    }

    if (tt == qt) {  // only the diagonal tile can mask anything
      const int c0 = tt * 64;
#pragma unroll
      for (int i = 0; i < 4; i++)
#pragma unroll
        for (int r = 0; r < 4; r++) {
          int kcol = c0 + i * 16 + quad * 4 + r;
          if (kcol > qrow) st[i][r] = -3.0e38f;
        }
    }

    float tmax = -3.0e38f;
#pragma unroll
    for (int i = 0; i < 4; i++)
#pragma unroll
      for (int r = 0; r < 4; r++) tmax = fmaxf(tmax, st[i][r]);
    tmax = fmaxf(tmax, __shfl_xor(tmax, 16));
    tmax = fmaxf(tmax, __shfl_xor(tmax, 32));

    if (!__all(tmax <= m_cur + 8.0f)) {  // defer-max (T13)
      float m_new = fmaxf(m_cur, tmax);
      float alpha = __expf(m_cur - m_new);
      l_sum *= alpha;
#pragma unroll
      for (int r = 0; r < 4; r++) {
        float ar = __shfl(alpha, quad * 4 + r);
#pragma unroll
        for (int j = 0; j < 8; j++) accO[j][r] *= ar;
      }
      m_cur = m_new;
    }

    float psum = 0.f;
#pragma unroll
    for (int i = 0; i < 4; i++) {
      us4 pv;
      u16* pp = (u16*)&pv;
#pragma unroll
      for (int r = 0; r < 4; r++) {
        float pe = __expf(st[i][r] - m_cur);
        psum += pe;
        pp[r] = f2bf(pe);
      }
      *(us4*)(lP + l15 * 72 + i * 16 + quad * 4) = pv;
    }
    psum += __shfl_xor(psum, 16);
    psum += __shfl_xor(psum, 32);
    l_sum += psum;

    bf16x8 pf[2];
#pragma unroll
    for (int ks = 0; ks < 2; ks++)
      pf[ks] = *(const bf16x8*)(lP + l15 * 72 + ks * 32 + quad * 8);
#pragma unroll
    for (int j = 0; j < 8; j++) {
      int dd = j * 16 + l15;
#pragma unroll
      for (int ks = 0; ks < 2; ks++) {
        int lc = ks * 4 + quad;
        bf16x8 vf = *(const bf16x8*)(lVd + dd * 64 + ((lc ^ (dd & 7)) * 8));
        accO[j] = MFMA16(pf[ks], vf, accO[j], 0, 0, 0);
      }
    }

    __builtin_amdgcn_s_barrier();          // all waves done reading buf db
    if (tt + 2 < ntiles) STAGE_KV(tt + 2, db);
    if (tt + 1 < ntiles) {
      if (tt + 2 < ntiles) asm volatile("s_waitcnt vmcnt(8)" ::: "memory");
      else                 asm volatile("s_waitcnt vmcnt(0)" ::: "memory");
    }
    __builtin_amdgcn_s_barrier();          // buf dn (tile tt+1) fully landed
  }
#undef STAGE_KV

  float linv = 1.0f / l_sum;
#pragma unroll
  for (int r = 0; r < 4; r++) {
    float lr = __shfl(linv, quad * 4 + r);
    int row = q0 + w * 16 + quad * 4 + r;
#pragma unroll
    for (int j = 0; j < 8; j++) {
      int col = h * HD + j * 16 + l15;
      ab[(size_t)row * HID + col] = f2bf(accO[j][r] * lr);
    }
  }
}

// ---------------- launch ----------------------------------------------------
extern "C" void kernel_launch(void* const* d_in, const int* in_sizes, int n_in,
                              void* d_out, int out_size, void* d_ws, size_t ws_size,
                              hipStream_t stream) {
  const float* x    = (const float*)d_in[0];
  const float* wq   = (const float*)d_in[1];
  const float* wk   = (const float*)d_in[2];
  const float* wv   = (const float*)d_in[3];
  const float* wo   = (const float*)d_in[4];
  const float* qnw  = (const float*)d_in[5];
  const float* knw  = (const float*)d_in[6];
  const float* cosT = (const float*)d_in[7];
  const float* sinT = (const float*)d_in[8];
  const int* positions = (const int*)d_in[11];

  static int attr_done = 0;
  if (!attr_done) {
    hipFuncSetAttribute((const void*)gemm_qkv8,
                        hipFuncAttributeMaxDynamicSharedMemorySize, 114688);
    hipFuncSetAttribute((const void*)gemm_outF,
                        hipFuncAttributeMaxDynamicSharedMemorySize, 98304);
    hipFuncSetAttribute((const void*)attn_fwd,
                        hipFuncAttributeMaxDynamicSharedMemorySize, 74752);
    attr_done = 1;
  }

  char* ws = (char*)d_ws;
  u16* xb    = (u16*)(ws + 0ULL);          //  16 MB  x bf16
  u16* wqkvb = (u16*)(ws + 16777216ULL);   //  48 MB  [wq;wk;wv] bf16 (6144x4096)
  u16* wob   = (u16*)(ws + 67108864ULL);   //  32 MB  wo bf16
  u16* Qp    = (u16*)(ws + 100663296ULL);  //  16 MB  q proj (S x 4096)
  u16* Kp    = (u16*)(ws + 117440512ULL);  //   4 MB  k proj (S x 1024)
  u16* vt    = (u16*)(ws + 121634816ULL);  //   4 MB  V^T (1024 x S)
  u16* qbh   = (u16*)(ws + 125829120ULL);  //  16 MB  q heads (NH,S,D)
  u16* kbh   = (u16*)(ws + 142606336ULL);  //   4 MB  k heads (KVH,S,D)
  u16* ab    = (u16*)(ws + 146800640ULL);  //  16 MB  attn out (S x 4096)

  cvt_all<<<32768, 256, 0, stream>>>(x, wq, wk, wv, xb, wqkvb);

  gemm_qkv8<<<256, 512, 114688, stream>>>(xb, wqkvb, Qp, Kp, vt);

  rope_all<<<20480, 256, 0, stream>>>(Qp, Kp, qnw, knw, cosT, sinT, positions,
                                      qbh, kbh);

  attn_fwd<<<dim3(NH + 12, S_LEN / 64), 256, 74752, stream>>>(qbh, kbh, vt, ab,
                                                              wo, wob);

  gemm_outF<<<256, 512, 98304, stream>>>(ab, wob, (float*)d_out);
}